// Round 4
// baseline (403.087 us; speedup 1.0000x reference)
//
#include <hip/hip_runtime.h>
#include <math.h>

// Problem dims
#define BL    6
#define CCH   64
#define C3    192
#define L2    1024
#define DIC   128
#define NST   16
#define K4    4
#define PSTR  1088   // padded plane stride: 34 rows * 32 cols

#define LOG2E 1.44269504088896340736f
#define LN2C  0.69314718055994530942f

__device__ __forceinline__ float fexp(float x){ return __builtin_amdgcn_exp2f(x*LOG2E); }
__device__ __forceinline__ float fsilu(float x){ return x / (1.f + fexp(-x)); }
__device__ __forceinline__ float fsoftplus(float x){
  if (x > 20.f) return x;
  return __builtin_amdgcn_logf(1.f + fexp(x)) * LN2C;
}
__device__ __forceinline__ float fgelu(float x){
  return 0.5f*x*(1.f + erff(x*0.70710678118654752440f));
}

// ---------------- A: per-pixel channel LayerNorm of frames + concat [dz, frames_n, sigma]
__global__ __launch_bounds__(256) void k_ln2d(const float* __restrict__ img,
    const float* __restrict__ dz, const float* __restrict__ sg,
    const float* __restrict__ g, const float* __restrict__ b, float* __restrict__ x3c){
  __shared__ float ps[4][64], pq[4][64];
  int s = blockIdx.x >> 4;
  int lane = threadIdx.x & 63;
  int cg = threadIdx.x >> 6;
  int p = ((blockIdx.x & 15) << 6) + lane;
  int bsmp = s/3;
  const float* fr = img + (size_t)s*CCH*L2;
  float vals[16]; float sm=0.f, sq=0.f;
  #pragma unroll
  for (int j=0;j<16;++j){
    int c = cg*16+j;
    float v = fr[c*L2+p];
    vals[j]=v; sm+=v; sq+=v*v;
  }
  ps[cg][lane]=sm; pq[cg][lane]=sq;
  __syncthreads();
  sm = ps[0][lane]+ps[1][lane]+ps[2][lane]+ps[3][lane];
  sq = pq[0][lane]+pq[1][lane]+pq[2][lane]+pq[3][lane];
  float mean = sm*(1.f/CCH); float var = sq*(1.f/CCH) - mean*mean;
  float rs = rsqrtf(var + 1e-6f);
  float* o = x3c + (size_t)s*C3*L2;
  const float* dzp = dz + (size_t)bsmp*CCH*L2;
  const float* sgp = sg + (size_t)bsmp*CCH*L2;
  #pragma unroll
  for (int j=0;j<16;++j){
    int c = cg*16+j;
    o[c*L2+p] = dzp[c*L2+p];
    o[(CCH+c)*L2+p] = (vals[j]-mean)*rs*g[c] + b[c];
    o[(2*CCH+c)*L2+p] = sgp[c*L2+p];
  }
}

// ---------------- GroupNorm(1) stats: 2-stage
__global__ __launch_bounds__(256) void k_gnstats_part(const float* __restrict__ x,
    int elems_per_s, float* __restrict__ psum, float* __restrict__ psq){
  int s = blockIdx.x >> 4; int i = blockIdx.x & 15;
  int chunk = elems_per_s >> 4;
  int tid = threadIdx.x;
  const float* xs = x + (size_t)s*elems_per_s + (size_t)i*chunk;
  float sm=0.f, sq=0.f;
  for (int idx = tid*4; idx < chunk; idx += 1024){
    float4 v = *(const float4*)(xs+idx);
    sm += v.x+v.y+v.z+v.w;
    sq += v.x*v.x+v.y*v.y+v.z*v.z+v.w*v.w;
  }
  for (int m=1;m<64;m<<=1){ sm+=__shfl_xor(sm,m,64); sq+=__shfl_xor(sq,m,64); }
  __shared__ float s_sm[4], s_sq[4];
  int wv = tid>>6;
  if ((tid&63)==0){ s_sm[wv]=sm; s_sq[wv]=sq; }
  __syncthreads();
  if (tid==0){
    psum[s*16+i] = s_sm[0]+s_sm[1]+s_sm[2]+s_sm[3];
    psq [s*16+i] = s_sq[0]+s_sq[1]+s_sq[2]+s_sq[3];
  }
}

__global__ __launch_bounds__(64) void k_gnstats_final(const float* __restrict__ psum,
    const float* __restrict__ psq, int elems_per_s, float eps, float* __restrict__ stats){
  int s = blockIdx.x; int lane = threadIdx.x;
  float sm = lane<16 ? psum[s*16+lane] : 0.f;
  float sq = lane<16 ? psq [s*16+lane] : 0.f;
  for (int m=1;m<16;m<<=1){ sm+=__shfl_xor(sm,m,64); sq+=__shfl_xor(sq,m,64); }
  if (lane==0){
    float mean = sm/elems_per_s; float var = sq/elems_per_s - mean*mean;
    stats[s*2] = mean; stats[s*2+1] = rsqrtf(var+eps);
  }
}

// ---------------- apply GN affine + SiLU, write PADDED plane (zero pad rows)
__global__ __launch_bounds__(256) void k_gnact_pad(const float* __restrict__ x,
    const float* __restrict__ stats, const float* __restrict__ g, const float* __restrict__ b,
    int ch, float* __restrict__ out){
  int bx = blockIdx.x;
  int s = bx / ch; int c = bx % ch;
  int tid = threadIdx.x;
  float mean = stats[s*2], rs = stats[s*2+1];
  float gc = g[c]*rs; float bc = b[c] - mean*rs*g[c];
  float4 v = *(const float4*)(x + (size_t)bx*1024 + tid*4);
  float4 o; o.x = fsilu(v.x*gc+bc); o.y = fsilu(v.y*gc+bc);
  o.z = fsilu(v.z*gc+bc); o.w = fsilu(v.w*gc+bc);
  float* pl = out + (size_t)bx*PSTR;
  *(float4*)(pl + 32 + tid*4) = o;
  float4 z4 = make_float4(0.f,0.f,0.f,0.f);
  if (tid < 8)  *(float4*)(pl + tid*4) = z4;
  else if (tid < 16) *(float4*)(pl + 1056 + (tid-8)*4) = z4;
}

// conv row helper: accumulate 3 taps for 2 output channels over a 4-px quad
__device__ __forceinline__ void conv_row_acc(float4& a0, float4& a1, float4 mid, float lf, float rt,
    const float* wp0, const float* wp1){
  float w0=wp0[0], w1=wp0[1], w2=wp0[2];
  a0.x = fmaf(w0,lf,   fmaf(w1,mid.x, fmaf(w2,mid.y, a0.x)));
  a0.y = fmaf(w0,mid.x,fmaf(w1,mid.y, fmaf(w2,mid.z, a0.y)));
  a0.z = fmaf(w0,mid.y,fmaf(w1,mid.z, fmaf(w2,mid.w, a0.z)));
  a0.w = fmaf(w0,mid.z,fmaf(w1,mid.w, fmaf(w2,rt,    a0.w)));
  float v0=wp1[0], v1=wp1[1], v2=wp1[2];
  a1.x = fmaf(v0,lf,   fmaf(v1,mid.x, fmaf(v2,mid.y, a1.x)));
  a1.y = fmaf(v0,mid.x,fmaf(v1,mid.y, fmaf(v2,mid.z, a1.y)));
  a1.z = fmaf(v0,mid.y,fmaf(v1,mid.z, fmaf(v2,mid.w, a1.z)));
  a1.w = fmaf(v0,mid.z,fmaf(v1,mid.w, fmaf(v2,rt,    a1.w)));
}

__device__ __forceinline__ void conv_ci_body(float4 m0, float4 m1, float4 m2, int q,
    const float* wp0, const float* wp1, float4& a0, float4& a1){
  float lf0=__shfl_up(m0.w,1,64), rt0=__shfl_down(m0.x,1,64);
  float lf1=__shfl_up(m1.w,1,64), rt1=__shfl_down(m1.x,1,64);
  float lf2=__shfl_up(m2.w,1,64), rt2=__shfl_down(m2.x,1,64);
  if (q==0){ lf0=0.f; lf1=0.f; lf2=0.f; }
  if (q==7){ rt0=0.f; rt1=0.f; rt2=0.f; }
  conv_row_acc(a0,a1,m0,lf0,rt0, wp0+0, wp1+0);
  conv_row_acc(a0,a1,m1,lf1,rt1, wp0+3, wp1+3);
  conv_row_acc(a0,a1,m2,lf2,rt2, wp0+6, wp1+6);
}

// ---------------- conv1: 192ci -> 64co, split-K=4 (48 ci each), padded input
__global__ __launch_bounds__(256) void k_conv1_split(const float* __restrict__ xact,
    const float* __restrict__ w, float* __restrict__ part){
  int bx = blockIdx.x; int kk = bx&3; int cop=(bx>>2)&31; int s=bx>>7;
  int co0 = cop*2, co1 = co0+1;
  int tid = threadIdx.x; int row = tid>>3; int q = tid&7; int col0 = q*4;
  float4 a0 = make_float4(0.f,0.f,0.f,0.f);
  float4 a1 = make_float4(0.f,0.f,0.f,0.f);
  int ci0 = kk*48;
  const float* pl = xact + ((size_t)s*C3 + ci0)*PSTR + row*32 + col0;
  const float* wp0 = w + (size_t)(co0*C3 + ci0)*9;
  const float* wp1 = w + (size_t)(co1*C3 + ci0)*9;
  float4 m0 = *(const float4*)(pl);
  float4 m1 = *(const float4*)(pl+32);
  float4 m2 = *(const float4*)(pl+64);
  #pragma unroll 2
  for (int i=0;i<48;++i){
    const float* pn = pl + (i<47 ? PSTR : 0);
    float4 n0 = *(const float4*)(pn);
    float4 n1 = *(const float4*)(pn+32);
    float4 n2 = *(const float4*)(pn+64);
    conv_ci_body(m0,m1,m2,q, wp0, wp1, a0, a1);
    wp0 += 9; wp1 += 9; pl = pn; m0=n0; m1=n1; m2=n2;
  }
  float* pp = part + (size_t)kk*(BL*CCH*L2) + ((size_t)s*CCH+co0)*L2 + row*32+col0;
  *(float4*)pp = a0;
  *(float4*)(pp+L2) = a1;
}

__global__ __launch_bounds__(256) void k_reduce1(const float* __restrict__ part,
    const float* __restrict__ bias, float* __restrict__ h1){
  int co = blockIdx.x & 63; int s = blockIdx.x >> 6;
  size_t ofs = ((size_t)s*CCH+co)*L2 + threadIdx.x*4;
  const size_t stride = (size_t)BL*CCH*L2;
  float4 r0 = *(const float4*)(part + ofs);
  float4 r1 = *(const float4*)(part + stride + ofs);
  float4 r2 = *(const float4*)(part + 2*stride + ofs);
  float4 r3 = *(const float4*)(part + 3*stride + ofs);
  float bv = bias[co];
  float4 o;
  o.x = r0.x+r1.x+r2.x+r3.x+bv;
  o.y = r0.y+r1.y+r2.y+r3.y+bv;
  o.z = r0.z+r1.z+r2.z+r3.z+bv;
  o.w = r0.w+r1.w+r2.w+r3.w+bv;
  *(float4*)(h1 + ofs) = o;
}

// ---------------- conv2 3x3 (64ci, roles 0/1 = 32ci each) + skip 1x1 (role 2)
__global__ __launch_bounds__(256) void k_conv2_split(const float* __restrict__ xact2,
    const float* __restrict__ x3c, const float* __restrict__ w2,
    const float* __restrict__ wsk, float* __restrict__ part){
  int t = blockIdx.x; int role = t % 3; t /= 3;
  int cop = t & 31; int s = t >> 5;
  int co0 = cop*2, co1 = co0+1;
  int tid = threadIdx.x; int row = tid>>3; int q = tid&7; int col0 = q*4;
  int p = row*32+col0;
  float4 a0 = make_float4(0.f,0.f,0.f,0.f);
  float4 a1 = make_float4(0.f,0.f,0.f,0.f);
  if (role < 2){
    int ci0 = role*32;
    const float* pl = xact2 + ((size_t)s*CCH + ci0)*PSTR + row*32 + col0;
    const float* wp0 = w2 + (size_t)(co0*CCH + ci0)*9;
    const float* wp1 = w2 + (size_t)(co1*CCH + ci0)*9;
    float4 m0 = *(const float4*)(pl);
    float4 m1 = *(const float4*)(pl+32);
    float4 m2 = *(const float4*)(pl+64);
    #pragma unroll 2
    for (int i=0;i<32;++i){
      const float* pn = pl + (i<31 ? PSTR : 0);
      float4 n0 = *(const float4*)(pn);
      float4 n1 = *(const float4*)(pn+32);
      float4 n2 = *(const float4*)(pn+64);
      conv_ci_body(m0,m1,m2,q, wp0, wp1, a0, a1);
      wp0 += 9; wp1 += 9; pl = pn; m0=n0; m1=n1; m2=n2;
    }
  } else {
    const float* x3 = x3c + (size_t)s*C3*L2 + p;
    #pragma unroll 4
    for (int ci=0; ci<C3; ++ci){
      float4 v = *(const float4*)(x3 + (size_t)ci*L2);
      float ws0 = wsk[co0*C3+ci], ws1 = wsk[co1*C3+ci];
      a0.x = fmaf(ws0,v.x,a0.x); a0.y = fmaf(ws0,v.y,a0.y); a0.z = fmaf(ws0,v.z,a0.z); a0.w = fmaf(ws0,v.w,a0.w);
      a1.x = fmaf(ws1,v.x,a1.x); a1.y = fmaf(ws1,v.y,a1.y); a1.z = fmaf(ws1,v.z,a1.z); a1.w = fmaf(ws1,v.w,a1.w);
    }
  }
  float* pp = part + (size_t)role*(BL*CCH*L2) + ((size_t)s*CCH+co0)*L2 + p;
  *(float4*)pp = a0;
  *(float4*)(pp+L2) = a1;
}

__global__ __launch_bounds__(256) void k_reduce2(const float* __restrict__ part,
    const float* __restrict__ b2, const float* __restrict__ bsk,
    float* __restrict__ xp, float* __restrict__ x_cmaj){
  int co = blockIdx.x & 63; int s = blockIdx.x >> 6;
  int p = threadIdx.x*4;
  size_t ofs = ((size_t)s*CCH+co)*L2 + p;
  const size_t stride = (size_t)BL*CCH*L2;
  float4 r0 = *(const float4*)(part + ofs);
  float4 r1 = *(const float4*)(part + stride + ofs);
  float4 r2 = *(const float4*)(part + 2*stride + ofs);
  float bv = b2[co]+bsk[co];
  float4 o;
  o.x = r0.x+r1.x+r2.x+bv;
  o.y = r0.y+r1.y+r2.y+bv;
  o.z = r0.z+r1.z+r2.z+bv;
  o.w = r0.w+r1.w+r2.w+bv;
  *(float4*)(x_cmaj + ofs) = o;
  float* xpb = xp + ((size_t)s*L2 + p)*CCH + co;
  xpb[0] = o.x; xpb[CCH] = o.y; xpb[2*CCH] = o.z; xpb[3*CCH] = o.w;
}

// ---------------- H: ln1 + in_proj; xc (c-major) and z (c-major)
__global__ __launch_bounds__(256) void k_ln1_inproj(const float* __restrict__ xp,
    const float* __restrict__ g, const float* __restrict__ b, const float* __restrict__ W,
    float* __restrict__ xc, float* __restrict__ z_t){
  __shared__ float xn_s[64*65];
  int s = blockIdx.x >> 4; int p0 = (blockIdx.x & 15)*64;
  int tid = threadIdx.x; int wv = __builtin_amdgcn_readfirstlane(tid>>6); int lane = tid&63;
  for (int j=0;j<16;++j){
    int pl = wv*16 + j; int p = p0 + pl;
    float v = xp[((size_t)s*L2 + p)*CCH + lane];
    float sm = v, sq = v*v;
    for (int m=1;m<64;m<<=1){ sm += __shfl_xor(sm,m,64); sq += __shfl_xor(sq,m,64); }
    float mean = sm*(1.f/64.f); float var = sq*(1.f/64.f) - mean*mean;
    float rs = rsqrtf(var + 1e-5f);
    xn_s[pl*65 + lane] = (v-mean)*rs*g[lane] + b[lane];
  }
  __syncthreads();
  int px_l = tid & 63;
  int og = __builtin_amdgcn_readfirstlane(tid >> 6);
  int o0 = og*64;
  float acc[64];
  #pragma unroll
  for (int oi=0;oi<64;++oi) acc[oi]=0.f;
  for (int c=0;c<64;++c){
    float xv = xn_s[px_l*65 + c];
    #pragma unroll
    for (int oi=0;oi<64;++oi) acc[oi] = fmaf(W[(o0+oi)*64 + c], xv, acc[oi]);
  }
  int p = p0 + px_l;
  if (og < 2){
    #pragma unroll
    for (int oi=0;oi<64;++oi) xc[((size_t)s*DIC + o0 + oi)*L2 + p] = acc[oi];
  } else {
    #pragma unroll
    for (int oi=0;oi<64;++oi) z_t[((size_t)s*DIC + (o0-128) + oi)*L2 + p] = acc[oi];
  }
}

// ---------------- I: depthwise 3x3 conv + bias + SiLU
__global__ __launch_bounds__(256) void k_dwconv(const float* __restrict__ xc,
    const float* __restrict__ w, const float* __restrict__ bias, float* __restrict__ xconv){
  int bx = blockIdx.x; int dch = bx & 127; int s = bx >> 7;
  int tid = threadIdx.x; int row = tid>>3; int q = tid&7; int col0 = q*4;
  const float* xr = xc + ((size_t)s*DIC+dch)*L2;
  const float* wp = w + dch*9;
  float bv = bias[dch];
  float4 acc = make_float4(bv,bv,bv,bv);
  #pragma unroll
  for (int dy=-1;dy<=1;++dy){
    int r = row+dy;
    float4 mid = make_float4(0.f,0.f,0.f,0.f);
    if (0<=r && r<32) mid = *(const float4*)(xr + r*32 + col0);
    float lf = __shfl_up(mid.w,1,64); if(q==0) lf=0.f;
    float rt = __shfl_down(mid.x,1,64); if(q==7) rt=0.f;
    float w0=wp[(dy+1)*3], w1=wp[(dy+1)*3+1], w2=wp[(dy+1)*3+2];
    acc.x = fmaf(w0,lf,   fmaf(w1,mid.x, fmaf(w2,mid.y, acc.x)));
    acc.y = fmaf(w0,mid.x,fmaf(w1,mid.y, fmaf(w2,mid.z, acc.y)));
    acc.z = fmaf(w0,mid.y,fmaf(w1,mid.z, fmaf(w2,mid.w, acc.z)));
    acc.w = fmaf(w0,mid.z,fmaf(w1,mid.w, fmaf(w2,rt,    acc.w)));
  }
  acc.x = fsilu(acc.x); acc.y = fsilu(acc.y); acc.z = fsilu(acc.z); acc.w = fsilu(acc.w);
  *(float4*)(xconv + ((size_t)s*DIC+dch)*L2 + row*32+col0) = acc;
}

// ---------------- transpose xconv [s][d][p] -> u_t [s][p][d] (LDS tiles 64d x 64p)
__global__ __launch_bounds__(256) void k_transp_u(const float* __restrict__ xconv,
    float* __restrict__ u_t){
  __shared__ float tb[64*65];
  int bx = blockIdx.x; int dh = bx & 1; int pg = (bx>>1)&15; int s = bx>>5;
  int tid = threadIdx.x;
  for (int i = tid; i < 64*16; i += 256){
    int dr = i>>4; int j4 = (i&15)*4;
    float4 v = *(const float4*)(xconv + ((size_t)(s*DIC + dh*64 + dr))*L2 + pg*64 + j4);
    tb[dr*65 + j4+0] = v.x; tb[dr*65 + j4+1] = v.y;
    tb[dr*65 + j4+2] = v.z; tb[dr*65 + j4+3] = v.w;
  }
  __syncthreads();
  for (int i = tid; i < 64*64; i += 256){
    int px = i>>6; int dd = i&63;
    u_t[((size_t)(s*L2) + pg*64 + px)*DIC + dh*64 + dd] = tb[dd*65 + px];
  }
}

// ---------------- J: x_proj: t36[s,k,c,p] = sum_d Xw[k,c,d]*xconv[s,d,p]
__global__ __launch_bounds__(256) void k_xproj(const float* __restrict__ xconv,
    const float* __restrict__ W, float* __restrict__ t36){
  int bx = blockIdx.x;
  int pg = bx & 3; int t = bx >> 2;
  int cg = t % 6; int t2 = t / 6;
  int k = t2 & 3; int s = t2 >> 2;
  int px = pg*256 + threadIdx.x;
  const float* xb = xconv + (size_t)s*DIC*L2 + px;
  const float* wb = W + (size_t)(k*36 + cg*6)*DIC;
  float acc[6] = {0.f,0.f,0.f,0.f,0.f,0.f};
  for (int dch=0; dch<DIC; ++dch){
    float v = xb[(size_t)dch*L2];
    #pragma unroll
    for (int ci=0; ci<6; ++ci) acc[ci] = fmaf(wb[ci*DIC+dch], v, acc[ci]);
  }
  float* ob = t36 + ((size_t)(s*4+k)*36 + cg*6)*L2 + px;
  #pragma unroll
  for (int ci=0;ci<6;++ci) ob[(size_t)ci*L2] = acc[ci];
}

// ---------------- K: dt (softplus, pixel-major d-contig) + B/C transpose to [p][16]
__global__ __launch_bounds__(256) void k_dt_bc(const float* __restrict__ t36,
    const float* __restrict__ dtw, const float* __restrict__ dtb,
    float* __restrict__ dtp, float* __restrict__ Bp, float* __restrict__ Cp){
  __shared__ float ld[36*68];
  int bx = blockIdx.x; int pg = bx & 15; int sk = bx >> 4;
  int k = sk & 3;
  int tid = threadIdx.x;
  const float* tbase = t36 + (size_t)sk*36*L2 + pg*64;
  for (int i = tid; i < 36*16; i += 256){
    int c = i>>4; int j4 = (i&15)*4;
    *(float4*)&ld[c*68 + j4] = *(const float4*)(tbase + (size_t)c*L2 + j4);
  }
  __syncthreads();
  int d = tid & 127; int half = tid >> 7;
  float w0 = dtw[(k*DIC+d)*4+0], w1 = dtw[(k*DIC+d)*4+1];
  float w2 = dtw[(k*DIC+d)*4+2], w3 = dtw[(k*DIC+d)*4+3];
  float bb = dtb[k*DIC+d];
  float* dout = dtp + ((size_t)sk*L2 + pg*64)*DIC + d;
  for (int pp = half*32; pp < half*32+32; ++pp){
    float r0 = ld[0*68+pp], r1 = ld[1*68+pp], r2 = ld[2*68+pp], r3 = ld[3*68+pp];
    float val = fsoftplus(fmaf(w0,r0,fmaf(w1,r1,fmaf(w2,r2,fmaf(w3,r3,bb)))));
    dout[(size_t)pp*DIC] = val;
  }
  float* Bb = Bp + ((size_t)sk*L2 + pg*64)*NST;
  float* Cb = Cp + ((size_t)sk*L2 + pg*64)*NST;
  for (int i = tid; i < 1024; i += 256){
    int pp = i>>4; int n = i&15;
    Bb[pp*NST + n] = ld[(4+n)*68 + pp];
    Cb[pp*NST + n] = ld[(20+n)*68 + pp];
  }
}

// scan-order pixel for direction k at step t (t, k uniform)
__device__ __forceinline__ int scan_pix(int t, int k){
  int tp = ((t&31)<<5) | (t>>5);
  if (k==0) return t;
  if (k==1) return tp;
  if (k==2) return 1023-t;
  return 1023-tp;
}

// ======== Selective scan, thread-per-d, 16 n-states in registers ========
// Phase A: per (s,k,chunk): local scan from h=0 -> hend[16], prodA[16]
__global__ __launch_bounds__(256) void k_scan_part2(const float* __restrict__ dtp,
    const float* __restrict__ u_t, const float* __restrict__ Bp,
    const float* __restrict__ A_logs, float* __restrict__ hend, float* __restrict__ prodA){
  int bx = blockIdx.x; int chp = bx & 7; int sk = bx >> 3;
  int k = sk & 3; int s = sk >> 2;
  int tid = threadIdx.x; int d = tid & 127; int ch = chp*2 + (tid>>7);
  float aco[16];
  {
    const float* ab = A_logs + (size_t)(k*DIC+d)*NST;
    #pragma unroll
    for (int n=0;n<16;++n) aco[n] = -LOG2E * fexp(ab[n]);
  }
  float h[16], Pr[16];
  #pragma unroll
  for (int n=0;n<16;++n){ h[n]=0.f; Pr[n]=1.f; }
  const float* db = dtp + (size_t)sk*L2*DIC + d;
  const float* ub = u_t + (size_t)s*L2*DIC + d;
  const float* Bb = Bp + (size_t)sk*L2*NST;
  #pragma unroll 2
  for (int j=0;j<64;++j){
    int t = ch*64 + j;
    int p = scan_pix(t, k);
    float dtv = db[(size_t)p*DIC];
    float uv  = ub[(size_t)p*DIC];
    float4 B0 = *(const float4*)(Bb + p*NST);
    float4 B1 = *(const float4*)(Bb + p*NST + 4);
    float4 B2 = *(const float4*)(Bb + p*NST + 8);
    float4 B3 = *(const float4*)(Bb + p*NST + 12);
    float tv = dtv*uv;
    #define PSTEP(NI, BV) { float a_ = __builtin_amdgcn_exp2f(dtv*aco[NI]); \
      h[NI] = fmaf(a_, h[NI], tv*(BV)); Pr[NI] *= a_; }
    PSTEP(0,B0.x) PSTEP(1,B0.y) PSTEP(2,B0.z) PSTEP(3,B0.w)
    PSTEP(4,B1.x) PSTEP(5,B1.y) PSTEP(6,B1.z) PSTEP(7,B1.w)
    PSTEP(8,B2.x) PSTEP(9,B2.y) PSTEP(10,B2.z) PSTEP(11,B2.w)
    PSTEP(12,B3.x) PSTEP(13,B3.y) PSTEP(14,B3.z) PSTEP(15,B3.w)
    #undef PSTEP
  }
  size_t base = ((size_t)(sk*16 + ch)*DIC + d)*NST;
  #pragma unroll
  for (int q4=0;q4<4;++q4){
    *(float4*)(hend + base + q4*4)  = make_float4(h[q4*4],h[q4*4+1],h[q4*4+2],h[q4*4+3]);
    *(float4*)(prodA + base + q4*4) = make_float4(Pr[q4*4],Pr[q4*4+1],Pr[q4*4+2],Pr[q4*4+3]);
  }
}

// Phase B: serial prefix over 16 chunks per (sk,d) -> Hin per chunk
__global__ __launch_bounds__(256) void k_scan_fix2(const float* __restrict__ hend,
    const float* __restrict__ prodA, float* __restrict__ Hin){
  int t = blockIdx.x*256 + threadIdx.x;   // 3072 = 24 sk * 128 d
  int d = t & 127; int sk = t >> 7;
  float H[16];
  #pragma unroll
  for (int n=0;n<16;++n) H[n]=0.f;
  for (int ch=0; ch<16; ++ch){
    size_t base = ((size_t)(sk*16 + ch)*DIC + d)*NST;
    #pragma unroll
    for (int q4=0;q4<4;++q4){
      float4 pa = *(const float4*)(prodA + base + q4*4);
      float4 he = *(const float4*)(hend + base + q4*4);
      *(float4*)(Hin + base + q4*4) = make_float4(H[q4*4],H[q4*4+1],H[q4*4+2],H[q4*4+3]);
      H[q4*4+0] = fmaf(pa.x, H[q4*4+0], he.x);
      H[q4*4+1] = fmaf(pa.y, H[q4*4+1], he.y);
      H[q4*4+2] = fmaf(pa.z, H[q4*4+2], he.z);
      H[q4*4+3] = fmaf(pa.w, H[q4*4+3], he.w);
    }
  }
}

// Phase C: re-run chunk from Hin, emit y at pixel p (inverse perm absorbed)
__global__ __launch_bounds__(256) void k_scan_y2(const float* __restrict__ dtp,
    const float* __restrict__ u_t, const float* __restrict__ Bp, const float* __restrict__ Cp,
    const float* __restrict__ A_logs, const float* __restrict__ Ds,
    const float* __restrict__ Hin, float* __restrict__ ys_t){
  int bx = blockIdx.x; int chp = bx & 7; int sk = bx >> 3;
  int k = sk & 3; int s = sk >> 2;
  int tid = threadIdx.x; int d = tid & 127; int ch = chp*2 + (tid>>7);
  float aco[16];
  {
    const float* ab = A_logs + (size_t)(k*DIC+d)*NST;
    #pragma unroll
    for (int n=0;n<16;++n) aco[n] = -LOG2E * fexp(ab[n]);
  }
  float Dv = Ds[k*DIC+d];
  float h[16];
  size_t hbase = ((size_t)(sk*16 + ch)*DIC + d)*NST;
  #pragma unroll
  for (int q4=0;q4<4;++q4){
    float4 hv = *(const float4*)(Hin + hbase + q4*4);
    h[q4*4]=hv.x; h[q4*4+1]=hv.y; h[q4*4+2]=hv.z; h[q4*4+3]=hv.w;
  }
  const float* db = dtp + (size_t)sk*L2*DIC + d;
  const float* ub = u_t + (size_t)s*L2*DIC + d;
  const float* Bb = Bp + (size_t)sk*L2*NST;
  const float* Cb = Cp + (size_t)sk*L2*NST;
  float* yb = ys_t + (size_t)sk*L2*DIC + d;
  #pragma unroll 2
  for (int j=0;j<64;++j){
    int t = ch*64 + j;
    int p = scan_pix(t, k);
    float dtv = db[(size_t)p*DIC];
    float uv  = ub[(size_t)p*DIC];
    float4 B0 = *(const float4*)(Bb + p*NST);
    float4 B1 = *(const float4*)(Bb + p*NST + 4);
    float4 B2 = *(const float4*)(Bb + p*NST + 8);
    float4 B3 = *(const float4*)(Bb + p*NST + 12);
    float4 C0 = *(const float4*)(Cb + p*NST);
    float4 C1 = *(const float4*)(Cb + p*NST + 4);
    float4 C2 = *(const float4*)(Cb + p*NST + 8);
    float4 C3v = *(const float4*)(Cb + p*NST + 12);
    float tv = dtv*uv;
    float y0=0.f, y1=0.f, y2=0.f, y3=0.f;
    #define YSTEP(NI, BV, CV, YA) { float a_ = __builtin_amdgcn_exp2f(dtv*aco[NI]); \
      h[NI] = fmaf(a_, h[NI], tv*(BV)); YA = fmaf(h[NI], (CV), YA); }
    YSTEP(0,B0.x,C0.x,y0) YSTEP(1,B0.y,C0.y,y1) YSTEP(2,B0.z,C0.z,y2) YSTEP(3,B0.w,C0.w,y3)
    YSTEP(4,B1.x,C1.x,y0) YSTEP(5,B1.y,C1.y,y1) YSTEP(6,B1.z,C1.z,y2) YSTEP(7,B1.w,C1.w,y3)
    YSTEP(8,B2.x,C2.x,y0) YSTEP(9,B2.y,C2.y,y1) YSTEP(10,B2.z,C2.z,y2) YSTEP(11,B2.w,C2.w,y3)
    YSTEP(12,B3.x,C3v.x,y0) YSTEP(13,B3.y,C3v.y,y1) YSTEP(14,B3.z,C3v.z,y2) YSTEP(15,B3.w,C3v.w,y3)
    #undef YSTEP
    yb[(size_t)p*DIC] = fmaf(uv, Dv, (y0+y1)+(y2+y3));
  }
}

// ---------------- M1: combine 4 dirs + out_norm LN(128) + *silu(z) -> yf (c-major)
__global__ __launch_bounds__(256) void k_combine2(const float* __restrict__ ys_t,
    const float* __restrict__ z_t, const float* __restrict__ g, const float* __restrict__ b,
    float* __restrict__ yf){
  __shared__ float yt[128*65];
  int s = blockIdx.x >> 4; int pg = blockIdx.x & 15;
  int tid = threadIdx.x;
  int wv = __builtin_amdgcn_readfirstlane(tid>>6); int lane = tid&63;
  int d0 = lane, d1 = lane+64;
  for (int i=0;i<16;++i){
    int px = i*4 + wv; int p = pg*64 + px;
    const float* yb = ys_t + ((size_t)(s*4)*L2 + p)*DIC;
    float ya = yb[d0] + yb[(size_t)L2*DIC + d0] + yb[(size_t)2*L2*DIC + d0] + yb[(size_t)3*L2*DIC + d0];
    float yc = yb[d1] + yb[(size_t)L2*DIC + d1] + yb[(size_t)2*L2*DIC + d1] + yb[(size_t)3*L2*DIC + d1];
    float sm = ya+yc, sq = ya*ya+yc*yc;
    for (int m=1;m<64;m<<=1){ sm+=__shfl_xor(sm,m,64); sq+=__shfl_xor(sq,m,64); }
    float mean = sm*(1.f/128.f); float var = sq*(1.f/128.f)-mean*mean;
    float rs = rsqrtf(var + 1e-5f);
    float yn0 = (ya-mean)*rs*g[d0] + b[d0];
    float yn1 = (yc-mean)*rs*g[d1] + b[d1];
    float zv0 = z_t[((size_t)s*DIC+d0)*L2 + p];
    float zv1 = z_t[((size_t)s*DIC+d1)*L2 + p];
    yt[d0*65 + px] = yn0 * fsilu(zv0);
    yt[d1*65 + px] = yn1 * fsilu(zv1);
  }
  __syncthreads();
  for (int idx = tid; idx < 128*64; idx += 256){
    int r = idx>>6; int jj = idx&63;
    yf[((size_t)s*DIC + r)*L2 + pg*64 + jj] = yt[r*65 + jj];
  }
}

// ---------------- M2a: xv = x + yf @ out_proj^T (c-major)
__global__ __launch_bounds__(256) void k_outproj(const float* __restrict__ yf,
    const float* __restrict__ x_cmaj, const float* __restrict__ W, float* __restrict__ xv){
  int bx = blockIdx.x; int cb = bx&3; int pg=(bx>>2)&15; int s=bx>>6;
  int lane = threadIdx.x&63;
  int cq = __builtin_amdgcn_readfirstlane(threadIdx.x>>6);
  int px = pg*64 + lane; int c0 = cb*16 + cq*4;
  const float* yb = yf + (size_t)s*DIC*L2 + px;
  float a0=0.f,a1=0.f,a2=0.f,a3=0.f;
  for (int dch=0;dch<DIC;++dch){
    float v = yb[(size_t)dch*L2];
    a0 = fmaf(W[(c0+0)*DIC+dch], v, a0);
    a1 = fmaf(W[(c0+1)*DIC+dch], v, a1);
    a2 = fmaf(W[(c0+2)*DIC+dch], v, a2);
    a3 = fmaf(W[(c0+3)*DIC+dch], v, a3);
  }
  size_t base = ((size_t)s*CCH+c0)*L2 + px;
  xv[base]        = x_cmaj[base]        + a0;
  xv[base+L2]     = x_cmaj[base+L2]     + a1;
  xv[base+2*L2]   = x_cmaj[base+2*L2]   + a2;
  xv[base+3*L2]   = x_cmaj[base+3*L2]   + a3;
}

// ---------------- M2b: ln2 + fc1 + gelu + fc2 + residual -> output (c-major)
__global__ __launch_bounds__(256) void k_mlp(const float* __restrict__ xv_in,
    const float* __restrict__ g, const float* __restrict__ b,
    const float* __restrict__ w1, const float* __restrict__ b1,
    const float* __restrict__ w2, const float* __restrict__ b2, float* __restrict__ out){
  __shared__ float xt[64*65];
  __shared__ float ts[64*65];
  int s = blockIdx.x >> 4; int p0 = (blockIdx.x & 15)*64;
  int tid = threadIdx.x; int lane = tid & 63;
  int grp = __builtin_amdgcn_readfirstlane(tid >> 6);
  for (int j=0;j<16;++j){
    int c = grp*16 + j;
    xt[c*65 + lane] = xv_in[((size_t)s*CCH + c)*L2 + p0 + lane];
  }
  __syncthreads();
  float sm=0.f, sq=0.f;
  for (int c=0;c<64;++c){ float v = xt[c*65+lane]; sm+=v; sq+=v*v; }
  float mean = sm*(1.f/64.f);
  float rs = rsqrtf(sq*(1.f/64.f) - mean*mean + 1e-5f);
  int o0 = grp*16;
  float t[16];
  #pragma unroll
  for (int oi=0;oi<16;++oi) t[oi] = b1[o0+oi];
  for (int c=0;c<64;++c){
    float xn = (xt[c*65+lane]-mean)*rs*g[c] + b[c];
    #pragma unroll
    for (int oi=0;oi<16;++oi) t[oi] = fmaf(xn, w1[(o0+oi)*64 + c], t[oi]);
  }
  #pragma unroll
  for (int oi=0;oi<16;++oi) ts[lane*65 + o0+oi] = fgelu(t[oi]);
  __syncthreads();
  int c0 = grp*16;
  float acc[16];
  #pragma unroll
  for (int ci=0;ci<16;++ci) acc[ci] = xt[(c0+ci)*65+lane] + b2[c0+ci];
  for (int o=0;o<64;++o){
    float tv = ts[lane*65 + o];
    #pragma unroll
    for (int ci=0;ci<16;++ci) acc[ci] = fmaf(tv, w2[(c0+ci)*64 + o], acc[ci]);
  }
  #pragma unroll
  for (int ci=0;ci<16;++ci) out[((size_t)s*CCH + c0+ci)*L2 + p0 + lane] = acc[ci];
}

extern "C" void kernel_launch(void* const* d_in, const int* in_sizes, int n_in,
                              void* d_out, int out_size, void* d_ws, size_t ws_size,
                              hipStream_t stream){
  (void)in_sizes; (void)n_in; (void)out_size; (void)ws_size;
  const float* img      = (const float*)d_in[0];
  const float* dz       = (const float*)d_in[1];
  const float* sg       = (const float*)d_in[2];
  const float* norm_g   = (const float*)d_in[3];
  const float* norm_b   = (const float*)d_in[4];
  const float* gn1_g    = (const float*)d_in[5];
  const float* gn1_b    = (const float*)d_in[6];
  const float* conv1_w  = (const float*)d_in[7];
  const float* conv1_b  = (const float*)d_in[8];
  const float* gn2_g    = (const float*)d_in[9];
  const float* gn2_b    = (const float*)d_in[10];
  const float* conv2_w  = (const float*)d_in[11];
  const float* conv2_b  = (const float*)d_in[12];
  const float* skip_w   = (const float*)d_in[13];
  const float* skip_b   = (const float*)d_in[14];
  const float* ln1_g    = (const float*)d_in[15];
  const float* ln1_b    = (const float*)d_in[16];
  const float* ln2_g    = (const float*)d_in[17];
  const float* ln2_b    = (const float*)d_in[18];
  const float* in_proj_w= (const float*)d_in[19];
  const float* dwconv_w = (const float*)d_in[20];
  const float* dwconv_b = (const float*)d_in[21];
  const float* x_proj_w = (const float*)d_in[22];
  const float* dt_proj_w= (const float*)d_in[23];
  const float* dt_proj_b= (const float*)d_in[24];
  const float* A_logs   = (const float*)d_in[25];
  const float* Ds       = (const float*)d_in[26];
  const float* out_norm_g = (const float*)d_in[27];
  const float* out_norm_b = (const float*)d_in[28];
  const float* out_proj_w = (const float*)d_in[29];
  const float* fc1_w    = (const float*)d_in[30];
  const float* fc1_b    = (const float*)d_in[31];
  const float* fc2_w    = (const float*)d_in[32];
  const float* fc2_b    = (const float*)d_in[33];

  float* ws = (float*)d_ws;
  float* x3c    = ws;                       // 1,179,648
  float* xact1  = x3c    + 1179648;         // 1,253,376 (padded)
  float* h1     = xact1  + 1253376;         // 393,216
  float* xact2  = h1     + 393216;          // 417,792 (padded)
  float* xp     = xact2  + 417792;          // 393,216
  float* x_cmaj = xp     + 393216;          // 393,216
  float* z_t    = x_cmaj + 393216;          // 786,432
  float* xc     = z_t    + 786432;          // 786,432
  float* xconv  = xc     + 786432;          // 786,432
  float* t36    = xconv  + 786432;          // 884,736
  float* dtp    = t36    + 884736;          // 3,145,728 (also hosts conv1 partials)
  float* ys_t   = dtp    + 3145728;         // 3,145,728 (also hosts conv2 partials)
  float* yf     = ys_t   + 3145728;         // 786,432
  float* xv     = yf     + 786432;          // 393,216
  float* psum   = xv     + 393216;          // 96
  float* psq    = psum   + 96;              // 96
  float* stats1 = psq    + 96;              // 12
  float* stats2 = stats1 + 12;              // 12
  // aliases into dead regions
  float* part1  = dtp;              // conv1 partials (4 x 393216), consumed before dtp written
  float* part2  = ys_t;             // conv2 partials (3 x 393216), consumed before ys_t written
  float* hend   = x3c;              // 786,432 (x3c dead after conv2_split)
  float* prodA  = x3c + 786432;     // 786,432
  float* Hin    = x3c + 1572864;    // 786,432 (within x3c+xact1)
  float* u_t    = h1;               // 786,432 (h1+xact2 dead after conv2_split)
  float* Bp     = xp;               // 393,216 (xp dead after ln1_inproj)
  float* Cp     = xc;               // 393,216 (xc dead after dwconv)

  k_ln2d<<<96, 256, 0, stream>>>(img, dz, sg, norm_g, norm_b, x3c);
  k_gnstats_part<<<96, 256, 0, stream>>>(x3c, C3*L2, psum, psq);
  k_gnstats_final<<<6, 64, 0, stream>>>(psum, psq, C3*L2, 1e-5f, stats1);
  k_gnact_pad<<<6*C3, 256, 0, stream>>>(x3c, stats1, gn1_g, gn1_b, C3, xact1);
  k_conv1_split<<<768, 256, 0, stream>>>(xact1, conv1_w, part1);
  k_reduce1<<<384, 256, 0, stream>>>(part1, conv1_b, h1);
  k_gnstats_part<<<96, 256, 0, stream>>>(h1, CCH*L2, psum, psq);
  k_gnstats_final<<<6, 64, 0, stream>>>(psum, psq, CCH*L2, 1e-5f, stats2);
  k_gnact_pad<<<6*CCH, 256, 0, stream>>>(h1, stats2, gn2_g, gn2_b, CCH, xact2);
  k_conv2_split<<<576, 256, 0, stream>>>(xact2, x3c, conv2_w, skip_w, part2);
  k_reduce2<<<384, 256, 0, stream>>>(part2, conv2_b, skip_b, xp, x_cmaj);
  k_ln1_inproj<<<96, 256, 0, stream>>>(xp, ln1_g, ln1_b, in_proj_w, xc, z_t);
  k_dwconv<<<768, 256, 0, stream>>>(xc, dwconv_w, dwconv_b, xconv);
  k_transp_u<<<192, 256, 0, stream>>>(xconv, u_t);
  k_xproj<<<576, 256, 0, stream>>>(xconv, x_proj_w, t36);
  k_dt_bc<<<384, 256, 0, stream>>>(t36, dt_proj_w, dt_proj_b, dtp, Bp, Cp);
  k_scan_part2<<<192, 256, 0, stream>>>(dtp, u_t, Bp, A_logs, hend, prodA);
  k_scan_fix2<<<12, 256, 0, stream>>>(hend, prodA, Hin);
  k_scan_y2<<<192, 256, 0, stream>>>(dtp, u_t, Bp, Cp, A_logs, Ds, Hin, ys_t);
  k_combine2<<<96, 256, 0, stream>>>(ys_t, z_t, out_norm_g, out_norm_b, yf);
  k_outproj<<<384, 256, 0, stream>>>(yf, x_cmaj, out_proj_w, xv);
  k_mlp<<<96, 256, 0, stream>>>(xv, ln2_g, ln2_b, fc1_w, fc1_b, fc2_w, fc2_b, (float*)d_out);
}

// Round 5
// 344.382 us; speedup vs baseline: 1.1705x; 1.1705x over previous
//
#include <hip/hip_runtime.h>
#include <math.h>

// Problem dims
#define BL    6
#define CCH   64
#define C3    192
#define L2    1024
#define DIC   128
#define NST   16
#define K4    4
#define PSTR  1088   // padded plane stride: 34 rows * 32 cols
#define NCH   32     // scan chunks per sequence (32 steps each)

#define LOG2E 1.44269504088896340736f
#define LN2C  0.69314718055994530942f

__device__ __forceinline__ float fexp(float x){ return __builtin_amdgcn_exp2f(x*LOG2E); }
__device__ __forceinline__ float fsilu(float x){ return x / (1.f + fexp(-x)); }
__device__ __forceinline__ float fsoftplus(float x){
  if (x > 20.f) return x;
  return __builtin_amdgcn_logf(1.f + fexp(x)) * LN2C;
}
__device__ __forceinline__ float fgelu(float x){
  return 0.5f*x*(1.f + erff(x*0.70710678118654752440f));
}

// ---------------- A: per-pixel channel LayerNorm of frames + concat [dz, frames_n, sigma]
__global__ __launch_bounds__(256) void k_ln2d(const float* __restrict__ img,
    const float* __restrict__ dz, const float* __restrict__ sg,
    const float* __restrict__ g, const float* __restrict__ b, float* __restrict__ x3c){
  __shared__ float ps[4][64], pq[4][64];
  int s = blockIdx.x >> 4;
  int lane = threadIdx.x & 63;
  int cg = threadIdx.x >> 6;
  int p = ((blockIdx.x & 15) << 6) + lane;
  int bsmp = s/3;
  const float* fr = img + (size_t)s*CCH*L2;
  float vals[16]; float sm=0.f, sq=0.f;
  #pragma unroll
  for (int j=0;j<16;++j){
    int c = cg*16+j;
    float v = fr[c*L2+p];
    vals[j]=v; sm+=v; sq+=v*v;
  }
  ps[cg][lane]=sm; pq[cg][lane]=sq;
  __syncthreads();
  sm = ps[0][lane]+ps[1][lane]+ps[2][lane]+ps[3][lane];
  sq = pq[0][lane]+pq[1][lane]+pq[2][lane]+pq[3][lane];
  float mean = sm*(1.f/CCH); float var = sq*(1.f/CCH) - mean*mean;
  float rs = rsqrtf(var + 1e-6f);
  float* o = x3c + (size_t)s*C3*L2;
  const float* dzp = dz + (size_t)bsmp*CCH*L2;
  const float* sgp = sg + (size_t)bsmp*CCH*L2;
  #pragma unroll
  for (int j=0;j<16;++j){
    int c = cg*16+j;
    o[c*L2+p] = dzp[c*L2+p];
    o[(CCH+c)*L2+p] = (vals[j]-mean)*rs*g[c] + b[c];
    o[(2*CCH+c)*L2+p] = sgp[c*L2+p];
  }
}

// ---------------- GroupNorm(1) stats: 2-stage
__global__ __launch_bounds__(256) void k_gnstats_part(const float* __restrict__ x,
    int elems_per_s, float* __restrict__ psum, float* __restrict__ psq){
  int s = blockIdx.x >> 4; int i = blockIdx.x & 15;
  int chunk = elems_per_s >> 4;
  int tid = threadIdx.x;
  const float* xs = x + (size_t)s*elems_per_s + (size_t)i*chunk;
  float sm=0.f, sq=0.f;
  for (int idx = tid*4; idx < chunk; idx += 1024){
    float4 v = *(const float4*)(xs+idx);
    sm += v.x+v.y+v.z+v.w;
    sq += v.x*v.x+v.y*v.y+v.z*v.z+v.w*v.w;
  }
  for (int m=1;m<64;m<<=1){ sm+=__shfl_xor(sm,m,64); sq+=__shfl_xor(sq,m,64); }
  __shared__ float s_sm[4], s_sq[4];
  int wv = tid>>6;
  if ((tid&63)==0){ s_sm[wv]=sm; s_sq[wv]=sq; }
  __syncthreads();
  if (tid==0){
    psum[s*16+i] = s_sm[0]+s_sm[1]+s_sm[2]+s_sm[3];
    psq [s*16+i] = s_sq[0]+s_sq[1]+s_sq[2]+s_sq[3];
  }
}

__global__ __launch_bounds__(64) void k_gnstats_final(const float* __restrict__ psum,
    const float* __restrict__ psq, int elems_per_s, float eps, float* __restrict__ stats){
  int s = blockIdx.x; int lane = threadIdx.x;
  float sm = lane<16 ? psum[s*16+lane] : 0.f;
  float sq = lane<16 ? psq [s*16+lane] : 0.f;
  for (int m=1;m<16;m<<=1){ sm+=__shfl_xor(sm,m,64); sq+=__shfl_xor(sq,m,64); }
  if (lane==0){
    float mean = sm/elems_per_s; float var = sq/elems_per_s - mean*mean;
    stats[s*2] = mean; stats[s*2+1] = rsqrtf(var+eps);
  }
}

// ---------------- apply GN affine + SiLU, write PADDED plane (zero pad rows)
__global__ __launch_bounds__(256) void k_gnact_pad(const float* __restrict__ x,
    const float* __restrict__ stats, const float* __restrict__ g, const float* __restrict__ b,
    int ch, float* __restrict__ out){
  int bx = blockIdx.x;
  int s = bx / ch; int c = bx % ch;
  int tid = threadIdx.x;
  float mean = stats[s*2], rs = stats[s*2+1];
  float gc = g[c]*rs; float bc = b[c] - mean*rs*g[c];
  float4 v = *(const float4*)(x + (size_t)bx*1024 + tid*4);
  float4 o; o.x = fsilu(v.x*gc+bc); o.y = fsilu(v.y*gc+bc);
  o.z = fsilu(v.z*gc+bc); o.w = fsilu(v.w*gc+bc);
  float* pl = out + (size_t)bx*PSTR;
  *(float4*)(pl + 32 + tid*4) = o;
  float4 z4 = make_float4(0.f,0.f,0.f,0.f);
  if (tid < 8)  *(float4*)(pl + tid*4) = z4;
  else if (tid < 16) *(float4*)(pl + 1056 + (tid-8)*4) = z4;
}

// conv row helper
__device__ __forceinline__ void conv_row_acc(float4& a0, float4& a1, float4 mid, float lf, float rt,
    const float* wp0, const float* wp1){
  float w0=wp0[0], w1=wp0[1], w2=wp0[2];
  a0.x = fmaf(w0,lf,   fmaf(w1,mid.x, fmaf(w2,mid.y, a0.x)));
  a0.y = fmaf(w0,mid.x,fmaf(w1,mid.y, fmaf(w2,mid.z, a0.y)));
  a0.z = fmaf(w0,mid.y,fmaf(w1,mid.z, fmaf(w2,mid.w, a0.z)));
  a0.w = fmaf(w0,mid.z,fmaf(w1,mid.w, fmaf(w2,rt,    a0.w)));
  float v0=wp1[0], v1=wp1[1], v2=wp1[2];
  a1.x = fmaf(v0,lf,   fmaf(v1,mid.x, fmaf(v2,mid.y, a1.x)));
  a1.y = fmaf(v0,mid.x,fmaf(v1,mid.y, fmaf(v2,mid.z, a1.y)));
  a1.z = fmaf(v0,mid.y,fmaf(v1,mid.z, fmaf(v2,mid.w, a1.z)));
  a1.w = fmaf(v0,mid.z,fmaf(v1,mid.w, fmaf(v2,rt,    a1.w)));
}

__device__ __forceinline__ void conv_ci_body(float4 m0, float4 m1, float4 m2, int q,
    const float* wp0, const float* wp1, float4& a0, float4& a1){
  float lf0=__shfl_up(m0.w,1,64), rt0=__shfl_down(m0.x,1,64);
  float lf1=__shfl_up(m1.w,1,64), rt1=__shfl_down(m1.x,1,64);
  float lf2=__shfl_up(m2.w,1,64), rt2=__shfl_down(m2.x,1,64);
  if (q==0){ lf0=0.f; lf1=0.f; lf2=0.f; }
  if (q==7){ rt0=0.f; rt1=0.f; rt2=0.f; }
  conv_row_acc(a0,a1,m0,lf0,rt0, wp0+0, wp1+0);
  conv_row_acc(a0,a1,m1,lf1,rt1, wp0+3, wp1+3);
  conv_row_acc(a0,a1,m2,lf2,rt2, wp0+6, wp1+6);
}

// ---------------- conv1: 192ci -> 64co, split-K=8 (24 ci each), padded input
__global__ __launch_bounds__(256) void k_conv1_split(const float* __restrict__ xact,
    const float* __restrict__ w, float* __restrict__ part){
  int bx = blockIdx.x; int kk = bx&7; int cop=(bx>>3)&31; int s=bx>>8;
  int co0 = cop*2, co1 = co0+1;
  int tid = threadIdx.x; int row = tid>>3; int q = tid&7; int col0 = q*4;
  float4 a0 = make_float4(0.f,0.f,0.f,0.f);
  float4 a1 = make_float4(0.f,0.f,0.f,0.f);
  int ci0 = kk*24;
  const float* pl = xact + ((size_t)s*C3 + ci0)*PSTR + row*32 + col0;
  const float* wp0 = w + (size_t)(co0*C3 + ci0)*9;
  const float* wp1 = w + (size_t)(co1*C3 + ci0)*9;
  float4 m0 = *(const float4*)(pl);
  float4 m1 = *(const float4*)(pl+32);
  float4 m2 = *(const float4*)(pl+64);
  #pragma unroll 2
  for (int i=0;i<24;++i){
    const float* pn = pl + (i<23 ? PSTR : 0);
    float4 n0 = *(const float4*)(pn);
    float4 n1 = *(const float4*)(pn+32);
    float4 n2 = *(const float4*)(pn+64);
    conv_ci_body(m0,m1,m2,q, wp0, wp1, a0, a1);
    wp0 += 9; wp1 += 9; pl = pn; m0=n0; m1=n1; m2=n2;
  }
  float* pp = part + (size_t)kk*(BL*CCH*L2) + ((size_t)s*CCH+co0)*L2 + row*32+col0;
  *(float4*)pp = a0;
  *(float4*)(pp+L2) = a1;
}

__global__ __launch_bounds__(256) void k_reduce1(const float* __restrict__ part,
    const float* __restrict__ bias, float* __restrict__ h1){
  int co = blockIdx.x & 63; int s = blockIdx.x >> 6;
  size_t ofs = ((size_t)s*CCH+co)*L2 + threadIdx.x*4;
  const size_t stride = (size_t)BL*CCH*L2;
  float4 acc = *(const float4*)(part + ofs);
  #pragma unroll
  for (int kk=1;kk<8;++kk){
    float4 r = *(const float4*)(part + (size_t)kk*stride + ofs);
    acc.x += r.x; acc.y += r.y; acc.z += r.z; acc.w += r.w;
  }
  float bv = bias[co];
  acc.x += bv; acc.y += bv; acc.z += bv; acc.w += bv;
  *(float4*)(h1 + ofs) = acc;
}

// ---------------- conv2 3x3 (64ci, roles 0/1 = 32ci each) + skip 1x1 (role 2)
__global__ __launch_bounds__(256) void k_conv2_split(const float* __restrict__ xact2,
    const float* __restrict__ x3c, const float* __restrict__ w2,
    const float* __restrict__ wsk, float* __restrict__ part){
  int t = blockIdx.x; int role = t % 3; t /= 3;
  int cop = t & 31; int s = t >> 5;
  int co0 = cop*2, co1 = co0+1;
  int tid = threadIdx.x; int row = tid>>3; int q = tid&7; int col0 = q*4;
  int p = row*32+col0;
  float4 a0 = make_float4(0.f,0.f,0.f,0.f);
  float4 a1 = make_float4(0.f,0.f,0.f,0.f);
  if (role < 2){
    int ci0 = role*32;
    const float* pl = xact2 + ((size_t)s*CCH + ci0)*PSTR + row*32 + col0;
    const float* wp0 = w2 + (size_t)(co0*CCH + ci0)*9;
    const float* wp1 = w2 + (size_t)(co1*CCH + ci0)*9;
    float4 m0 = *(const float4*)(pl);
    float4 m1 = *(const float4*)(pl+32);
    float4 m2 = *(const float4*)(pl+64);
    #pragma unroll 2
    for (int i=0;i<32;++i){
      const float* pn = pl + (i<31 ? PSTR : 0);
      float4 n0 = *(const float4*)(pn);
      float4 n1 = *(const float4*)(pn+32);
      float4 n2 = *(const float4*)(pn+64);
      conv_ci_body(m0,m1,m2,q, wp0, wp1, a0, a1);
      wp0 += 9; wp1 += 9; pl = pn; m0=n0; m1=n1; m2=n2;
    }
  } else {
    const float* x3 = x3c + (size_t)s*C3*L2 + p;
    #pragma unroll 4
    for (int ci=0; ci<C3; ++ci){
      float4 v = *(const float4*)(x3 + (size_t)ci*L2);
      float ws0 = wsk[co0*C3+ci], ws1 = wsk[co1*C3+ci];
      a0.x = fmaf(ws0,v.x,a0.x); a0.y = fmaf(ws0,v.y,a0.y); a0.z = fmaf(ws0,v.z,a0.z); a0.w = fmaf(ws0,v.w,a0.w);
      a1.x = fmaf(ws1,v.x,a1.x); a1.y = fmaf(ws1,v.y,a1.y); a1.z = fmaf(ws1,v.z,a1.z); a1.w = fmaf(ws1,v.w,a1.w);
    }
  }
  float* pp = part + (size_t)role*(BL*CCH*L2) + ((size_t)s*CCH+co0)*L2 + p;
  *(float4*)pp = a0;
  *(float4*)(pp+L2) = a1;
}

__global__ __launch_bounds__(256) void k_reduce2(const float* __restrict__ part,
    const float* __restrict__ b2, const float* __restrict__ bsk,
    float* __restrict__ xp, float* __restrict__ x_cmaj){
  int co = blockIdx.x & 63; int s = blockIdx.x >> 6;
  int p = threadIdx.x*4;
  size_t ofs = ((size_t)s*CCH+co)*L2 + p;
  const size_t stride = (size_t)BL*CCH*L2;
  float4 r0 = *(const float4*)(part + ofs);
  float4 r1 = *(const float4*)(part + stride + ofs);
  float4 r2 = *(const float4*)(part + 2*stride + ofs);
  float bv = b2[co]+bsk[co];
  float4 o;
  o.x = r0.x+r1.x+r2.x+bv;
  o.y = r0.y+r1.y+r2.y+bv;
  o.z = r0.z+r1.z+r2.z+bv;
  o.w = r0.w+r1.w+r2.w+bv;
  *(float4*)(x_cmaj + ofs) = o;
  float* xpb = xp + ((size_t)s*L2 + p)*CCH + co;
  xpb[0] = o.x; xpb[CCH] = o.y; xpb[2*CCH] = o.z; xpb[3*CCH] = o.w;
}

// ---------------- H: ln1 + in_proj, split-o: block = (s, pg, o-quadrant of 64)
__global__ __launch_bounds__(256) void k_ln1_inproj(const float* __restrict__ xp,
    const float* __restrict__ g, const float* __restrict__ b, const float* __restrict__ W,
    float* __restrict__ xc, float* __restrict__ z_t){
  __shared__ float xn_s[64*65];
  int bx = blockIdx.x; int oq = bx & 3; int pg = (bx>>2)&15; int s = bx>>6;
  int p0 = pg*64;
  int tid = threadIdx.x; int wv = __builtin_amdgcn_readfirstlane(tid>>6); int lane = tid&63;
  for (int j=0;j<16;++j){
    int pl = wv*16 + j; int p = p0 + pl;
    float v = xp[((size_t)s*L2 + p)*CCH + lane];
    float sm = v, sq = v*v;
    for (int m=1;m<64;m<<=1){ sm += __shfl_xor(sm,m,64); sq += __shfl_xor(sq,m,64); }
    float mean = sm*(1.f/64.f); float var = sq*(1.f/64.f) - mean*mean;
    float rs = rsqrtf(var + 1e-5f);
    xn_s[pl*65 + lane] = (v-mean)*rs*g[lane] + b[lane];
  }
  __syncthreads();
  int px_l = tid & 63;
  int og = __builtin_amdgcn_readfirstlane(tid >> 6);
  int o0 = oq*64 + og*16;
  float acc[16];
  #pragma unroll
  for (int oi=0;oi<16;++oi) acc[oi]=0.f;
  for (int c=0;c<64;++c){
    float xv = xn_s[px_l*65 + c];
    #pragma unroll
    for (int oi=0;oi<16;++oi) acc[oi] = fmaf(W[(o0+oi)*64 + c], xv, acc[oi]);
  }
  int p = p0 + px_l;
  if (oq < 2){
    #pragma unroll
    for (int oi=0;oi<16;++oi) xc[((size_t)s*DIC + o0 + oi)*L2 + p] = acc[oi];
  } else {
    #pragma unroll
    for (int oi=0;oi<16;++oi) z_t[((size_t)s*DIC + (o0-128) + oi)*L2 + p] = acc[oi];
  }
}

// ---------------- I: depthwise 3x3 conv + bias + SiLU
__global__ __launch_bounds__(256) void k_dwconv(const float* __restrict__ xc,
    const float* __restrict__ w, const float* __restrict__ bias, float* __restrict__ xconv){
  int bx = blockIdx.x; int dch = bx & 127; int s = bx >> 7;
  int tid = threadIdx.x; int row = tid>>3; int q = tid&7; int col0 = q*4;
  const float* xr = xc + ((size_t)s*DIC+dch)*L2;
  const float* wp = w + dch*9;
  float bv = bias[dch];
  float4 acc = make_float4(bv,bv,bv,bv);
  #pragma unroll
  for (int dy=-1;dy<=1;++dy){
    int r = row+dy;
    float4 mid = make_float4(0.f,0.f,0.f,0.f);
    if (0<=r && r<32) mid = *(const float4*)(xr + r*32 + col0);
    float lf = __shfl_up(mid.w,1,64); if(q==0) lf=0.f;
    float rt = __shfl_down(mid.x,1,64); if(q==7) rt=0.f;
    float w0=wp[(dy+1)*3], w1=wp[(dy+1)*3+1], w2=wp[(dy+1)*3+2];
    acc.x = fmaf(w0,lf,   fmaf(w1,mid.x, fmaf(w2,mid.y, acc.x)));
    acc.y = fmaf(w0,mid.x,fmaf(w1,mid.y, fmaf(w2,mid.z, acc.y)));
    acc.z = fmaf(w0,mid.y,fmaf(w1,mid.z, fmaf(w2,mid.w, acc.z)));
    acc.w = fmaf(w0,mid.z,fmaf(w1,mid.w, fmaf(w2,rt,    acc.w)));
  }
  acc.x = fsilu(acc.x); acc.y = fsilu(acc.y); acc.z = fsilu(acc.z); acc.w = fsilu(acc.w);
  *(float4*)(xconv + ((size_t)s*DIC+dch)*L2 + row*32+col0) = acc;
}

// ---------------- transpose xconv [s][d][p] -> u_t [s][p][d]
__global__ __launch_bounds__(256) void k_transp_u(const float* __restrict__ xconv,
    float* __restrict__ u_t){
  __shared__ float tb[64*65];
  int bx = blockIdx.x; int dh = bx & 1; int pg = (bx>>1)&15; int s = bx>>5;
  int tid = threadIdx.x;
  for (int i = tid; i < 64*16; i += 256){
    int dr = i>>4; int j4 = (i&15)*4;
    float4 v = *(const float4*)(xconv + ((size_t)(s*DIC + dh*64 + dr))*L2 + pg*64 + j4);
    tb[dr*65 + j4+0] = v.x; tb[dr*65 + j4+1] = v.y;
    tb[dr*65 + j4+2] = v.z; tb[dr*65 + j4+3] = v.w;
  }
  __syncthreads();
  for (int i = tid; i < 64*64; i += 256){
    int px = i>>6; int dd = i&63;
    u_t[((size_t)(s*L2) + pg*64 + px)*DIC + dh*64 + dd] = tb[dd*65 + px];
  }
}

// ---------------- J: x_proj
__global__ __launch_bounds__(256) void k_xproj(const float* __restrict__ xconv,
    const float* __restrict__ W, float* __restrict__ t36){
  int bx = blockIdx.x;
  int pg = bx & 3; int t = bx >> 2;
  int cg = t % 6; int t2 = t / 6;
  int k = t2 & 3; int s = t2 >> 2;
  int px = pg*256 + threadIdx.x;
  const float* xb = xconv + (size_t)s*DIC*L2 + px;
  const float* wb = W + (size_t)(k*36 + cg*6)*DIC;
  float acc[6] = {0.f,0.f,0.f,0.f,0.f,0.f};
  for (int dch=0; dch<DIC; ++dch){
    float v = xb[(size_t)dch*L2];
    #pragma unroll
    for (int ci=0; ci<6; ++ci) acc[ci] = fmaf(wb[ci*DIC+dch], v, acc[ci]);
  }
  float* ob = t36 + ((size_t)(s*4+k)*36 + cg*6)*L2 + px;
  #pragma unroll
  for (int ci=0;ci<6;++ci) ob[(size_t)ci*L2] = acc[ci];
}

// ---------------- K: dt (softplus, pixel-major d-contig) + B/C transpose to [p][16]
__global__ __launch_bounds__(256) void k_dt_bc(const float* __restrict__ t36,
    const float* __restrict__ dtw, const float* __restrict__ dtb,
    float* __restrict__ dtp, float* __restrict__ Bp, float* __restrict__ Cp){
  __shared__ float ld[36*68];
  int bx = blockIdx.x; int pg = bx & 15; int sk = bx >> 4;
  int k = sk & 3;
  int tid = threadIdx.x;
  const float* tbase = t36 + (size_t)sk*36*L2 + pg*64;
  for (int i = tid; i < 36*16; i += 256){
    int c = i>>4; int j4 = (i&15)*4;
    *(float4*)&ld[c*68 + j4] = *(const float4*)(tbase + (size_t)c*L2 + j4);
  }
  __syncthreads();
  int d = tid & 127; int half = tid >> 7;
  float w0 = dtw[(k*DIC+d)*4+0], w1 = dtw[(k*DIC+d)*4+1];
  float w2 = dtw[(k*DIC+d)*4+2], w3 = dtw[(k*DIC+d)*4+3];
  float bb = dtb[k*DIC+d];
  float* dout = dtp + ((size_t)sk*L2 + pg*64)*DIC + d;
  for (int pp = half*32; pp < half*32+32; ++pp){
    float r0 = ld[0*68+pp], r1 = ld[1*68+pp], r2 = ld[2*68+pp], r3 = ld[3*68+pp];
    float val = fsoftplus(fmaf(w0,r0,fmaf(w1,r1,fmaf(w2,r2,fmaf(w3,r3,bb)))));
    dout[(size_t)pp*DIC] = val;
  }
  float* Bb = Bp + ((size_t)sk*L2 + pg*64)*NST;
  float* Cb = Cp + ((size_t)sk*L2 + pg*64)*NST;
  for (int i = tid; i < 1024; i += 256){
    int pp = i>>4; int n = i&15;
    Bb[pp*NST + n] = ld[(4+n)*68 + pp];
    Cb[pp*NST + n] = ld[(20+n)*68 + pp];
  }
}

// scan pixel for direction k, chunk ch (32 steps), step j   [32-chunk alignment: t>>5 == ch]
__device__ __forceinline__ int scan_pix32(int ch, int j, int k){
  if (k==0) return ch*32 + j;
  if (k==1) return j*32 + ch;
  if (k==2) return 1023 - (ch*32 + j);
  return 1023 - (j*32 + ch);
}

struct StepB { float dtv, uv; float4 B0,B1,B2,B3; };
__device__ __forceinline__ StepB loadB(const float* db, const float* ub, const float* Bb, int p){
  StepB r;
  r.dtv = db[(size_t)p*DIC]; r.uv = ub[(size_t)p*DIC];
  const float* bp = Bb + p*NST;
  r.B0 = *(const float4*)bp; r.B1 = *(const float4*)(bp+4);
  r.B2 = *(const float4*)(bp+8); r.B3 = *(const float4*)(bp+12);
  return r;
}

// ======== Selective scan: 32 chunks x 32 steps, thread-per-d, manual prefetch ========
// Phase A: grid 384 = (sk, chp of 2 chunks); 256 thr = (d:128, ch:2)
__global__ __launch_bounds__(256,2) void k_scan_part3(const float* __restrict__ dtp,
    const float* __restrict__ u_t, const float* __restrict__ Bp,
    const float* __restrict__ A_logs, float* __restrict__ hend, float* __restrict__ prodA){
  int bx = blockIdx.x; int chp = bx & 15; int sk = bx >> 4;
  int k = sk & 3; int s = sk >> 2;
  int tid = threadIdx.x; int d = tid & 127; int ch = chp*2 + (tid>>7);
  float aco[16];
  {
    const float* ab = A_logs + (size_t)(k*DIC+d)*NST;
    #pragma unroll
    for (int n=0;n<16;++n) aco[n] = -LOG2E * fexp(ab[n]);
  }
  float h[16], Pr[16];
  #pragma unroll
  for (int n=0;n<16;++n){ h[n]=0.f; Pr[n]=1.f; }
  const float* db = dtp + (size_t)sk*L2*DIC + d;
  const float* ub = u_t + (size_t)s*L2*DIC + d;
  const float* Bb = Bp + (size_t)sk*L2*NST;
  StepB cur = loadB(db, ub, Bb, scan_pix32(ch, 0, k));
  #pragma unroll 4
  for (int j=0;j<32;++j){
    StepB nxt;
    if (j < 31) nxt = loadB(db, ub, Bb, scan_pix32(ch, j+1, k));
    float tv = cur.dtv*cur.uv;
    #define PSTEP(NI, BV) { float a_ = __builtin_amdgcn_exp2f(cur.dtv*aco[NI]); \
      h[NI] = fmaf(a_, h[NI], tv*(BV)); Pr[NI] *= a_; }
    PSTEP(0,cur.B0.x) PSTEP(1,cur.B0.y) PSTEP(2,cur.B0.z) PSTEP(3,cur.B0.w)
    PSTEP(4,cur.B1.x) PSTEP(5,cur.B1.y) PSTEP(6,cur.B1.z) PSTEP(7,cur.B1.w)
    PSTEP(8,cur.B2.x) PSTEP(9,cur.B2.y) PSTEP(10,cur.B2.z) PSTEP(11,cur.B2.w)
    PSTEP(12,cur.B3.x) PSTEP(13,cur.B3.y) PSTEP(14,cur.B3.z) PSTEP(15,cur.B3.w)
    #undef PSTEP
    cur = nxt;
  }
  size_t base = ((size_t)(sk*NCH + ch)*DIC + d)*NST;
  #pragma unroll
  for (int q4=0;q4<4;++q4){
    *(float4*)(hend + base + q4*4)  = make_float4(h[q4*4],h[q4*4+1],h[q4*4+2],h[q4*4+3]);
    *(float4*)(prodA + base + q4*4) = make_float4(Pr[q4*4],Pr[q4*4+1],Pr[q4*4+2],Pr[q4*4+3]);
  }
}

// Phase B: thread per (sk,d,n); Hin ALIASES prodA (same-thread load-before-store)
__global__ __launch_bounds__(256) void k_scan_fix3(const float* __restrict__ hend,
    float* prodA_Hin){
  int t = blockIdx.x*256 + threadIdx.x;   // 49152 = 24 sk * 128 d * 16 n
  int n = t & 15; int d = (t>>4) & 127; int sk = t >> 11;
  float H = 0.f;
  for (int ch=0; ch<NCH; ++ch){
    size_t idx = ((size_t)(sk*NCH + ch)*DIC + d)*NST + n;
    float pa = prodA_Hin[idx];
    float he = hend[idx];
    prodA_Hin[idx] = H;
    H = fmaf(pa, H, he);
  }
}

// Phase C: re-run chunk from Hin, emit y at pixel p
__global__ __launch_bounds__(256,2) void k_scan_y3(const float* __restrict__ dtp,
    const float* __restrict__ u_t, const float* __restrict__ Bp, const float* __restrict__ Cp,
    const float* __restrict__ A_logs, const float* __restrict__ Ds,
    const float* __restrict__ Hin, float* __restrict__ ys_t){
  int bx = blockIdx.x; int chp = bx & 15; int sk = bx >> 4;
  int k = sk & 3; int s = sk >> 2;
  int tid = threadIdx.x; int d = tid & 127; int ch = chp*2 + (tid>>7);
  float aco[16];
  {
    const float* ab = A_logs + (size_t)(k*DIC+d)*NST;
    #pragma unroll
    for (int n=0;n<16;++n) aco[n] = -LOG2E * fexp(ab[n]);
  }
  float Dv = Ds[k*DIC+d];
  float h[16];
  size_t hbase = ((size_t)(sk*NCH + ch)*DIC + d)*NST;
  #pragma unroll
  for (int q4=0;q4<4;++q4){
    float4 hv = *(const float4*)(Hin + hbase + q4*4);
    h[q4*4]=hv.x; h[q4*4+1]=hv.y; h[q4*4+2]=hv.z; h[q4*4+3]=hv.w;
  }
  const float* db = dtp + (size_t)sk*L2*DIC + d;
  const float* ub = u_t + (size_t)s*L2*DIC + d;
  const float* Bb = Bp + (size_t)sk*L2*NST;
  const float* Cb = Cp + (size_t)sk*L2*NST;
  float* yb = ys_t + (size_t)sk*L2*DIC + d;
  int pcur = scan_pix32(ch, 0, k);
  StepB cur = loadB(db, ub, Bb, pcur);
  float4 Cc0 = *(const float4*)(Cb + pcur*NST);
  float4 Cc1 = *(const float4*)(Cb + pcur*NST + 4);
  float4 Cc2 = *(const float4*)(Cb + pcur*NST + 8);
  float4 Cc3 = *(const float4*)(Cb + pcur*NST + 12);
  #pragma unroll 4
  for (int j=0;j<32;++j){
    StepB nxt; float4 Cn0, Cn1, Cn2, Cn3; int pn = pcur;
    if (j < 31){
      pn = scan_pix32(ch, j+1, k);
      nxt = loadB(db, ub, Bb, pn);
      Cn0 = *(const float4*)(Cb + pn*NST);
      Cn1 = *(const float4*)(Cb + pn*NST + 4);
      Cn2 = *(const float4*)(Cb + pn*NST + 8);
      Cn3 = *(const float4*)(Cb + pn*NST + 12);
    }
    float tv = cur.dtv*cur.uv;
    float y0=0.f, y1=0.f, y2=0.f, y3=0.f;
    #define YSTEP(NI, BV, CV, YA) { float a_ = __builtin_amdgcn_exp2f(cur.dtv*aco[NI]); \
      h[NI] = fmaf(a_, h[NI], tv*(BV)); YA = fmaf(h[NI], (CV), YA); }
    YSTEP(0,cur.B0.x,Cc0.x,y0) YSTEP(1,cur.B0.y,Cc0.y,y1) YSTEP(2,cur.B0.z,Cc0.z,y2) YSTEP(3,cur.B0.w,Cc0.w,y3)
    YSTEP(4,cur.B1.x,Cc1.x,y0) YSTEP(5,cur.B1.y,Cc1.y,y1) YSTEP(6,cur.B1.z,Cc1.z,y2) YSTEP(7,cur.B1.w,Cc1.w,y3)
    YSTEP(8,cur.B2.x,Cc2.x,y0) YSTEP(9,cur.B2.y,Cc2.y,y1) YSTEP(10,cur.B2.z,Cc2.z,y2) YSTEP(11,cur.B2.w,Cc2.w,y3)
    YSTEP(12,cur.B3.x,Cc3.x,y0) YSTEP(13,cur.B3.y,Cc3.y,y1) YSTEP(14,cur.B3.z,Cc3.z,y2) YSTEP(15,cur.B3.w,Cc3.w,y3)
    #undef YSTEP
    yb[(size_t)pcur*DIC] = fmaf(cur.uv, Dv, (y0+y1)+(y2+y3));
    cur = nxt; Cc0 = Cn0; Cc1 = Cn1; Cc2 = Cn2; Cc3 = Cn3; pcur = pn;
  }
}

// ---------------- M1: combine 4 dirs + out_norm LN(128) + *silu(z) -> yf (c-major)
__global__ __launch_bounds__(256) void k_combine2(const float* __restrict__ ys_t,
    const float* __restrict__ z_t, const float* __restrict__ g, const float* __restrict__ b,
    float* __restrict__ yf){
  __shared__ float yt[128*65];
  int s = blockIdx.x >> 4; int pg = blockIdx.x & 15;
  int tid = threadIdx.x;
  int wv = __builtin_amdgcn_readfirstlane(tid>>6); int lane = tid&63;
  int d0 = lane, d1 = lane+64;
  for (int i=0;i<16;++i){
    int px = i*4 + wv; int p = pg*64 + px;
    const float* yb = ys_t + ((size_t)(s*4)*L2 + p)*DIC;
    float ya = yb[d0] + yb[(size_t)L2*DIC + d0] + yb[(size_t)2*L2*DIC + d0] + yb[(size_t)3*L2*DIC + d0];
    float yc = yb[d1] + yb[(size_t)L2*DIC + d1] + yb[(size_t)2*L2*DIC + d1] + yb[(size_t)3*L2*DIC + d1];
    float sm = ya+yc, sq = ya*ya+yc*yc;
    for (int m=1;m<64;m<<=1){ sm+=__shfl_xor(sm,m,64); sq+=__shfl_xor(sq,m,64); }
    float mean = sm*(1.f/128.f); float var = sq*(1.f/128.f)-mean*mean;
    float rs = rsqrtf(var + 1e-5f);
    float yn0 = (ya-mean)*rs*g[d0] + b[d0];
    float yn1 = (yc-mean)*rs*g[d1] + b[d1];
    float zv0 = z_t[((size_t)s*DIC+d0)*L2 + p];
    float zv1 = z_t[((size_t)s*DIC+d1)*L2 + p];
    yt[d0*65 + px] = yn0 * fsilu(zv0);
    yt[d1*65 + px] = yn1 * fsilu(zv1);
  }
  __syncthreads();
  for (int idx = tid; idx < 128*64; idx += 256){
    int r = idx>>6; int jj = idx&63;
    yf[((size_t)s*DIC + r)*L2 + pg*64 + jj] = yt[r*65 + jj];
  }
}

// ---------------- M2a: xv = x + yf @ out_proj^T (c-major)
__global__ __launch_bounds__(256) void k_outproj(const float* __restrict__ yf,
    const float* __restrict__ x_cmaj, const float* __restrict__ W, float* __restrict__ xv){
  int bx = blockIdx.x; int cb = bx&3; int pg=(bx>>2)&15; int s=bx>>6;
  int lane = threadIdx.x&63;
  int cq = __builtin_amdgcn_readfirstlane(threadIdx.x>>6);
  int px = pg*64 + lane; int c0 = cb*16 + cq*4;
  const float* yb = yf + (size_t)s*DIC*L2 + px;
  float a0=0.f,a1=0.f,a2=0.f,a3=0.f;
  for (int dch=0;dch<DIC;++dch){
    float v = yb[(size_t)dch*L2];
    a0 = fmaf(W[(c0+0)*DIC+dch], v, a0);
    a1 = fmaf(W[(c0+1)*DIC+dch], v, a1);
    a2 = fmaf(W[(c0+2)*DIC+dch], v, a2);
    a3 = fmaf(W[(c0+3)*DIC+dch], v, a3);
  }
  size_t base = ((size_t)s*CCH+c0)*L2 + px;
  xv[base]        = x_cmaj[base]        + a0;
  xv[base+L2]     = x_cmaj[base+L2]     + a1;
  xv[base+2*L2]   = x_cmaj[base+2*L2]   + a2;
  xv[base+3*L2]   = x_cmaj[base+3*L2]   + a3;
}

// ---------------- M2b: ln2 + fc1 + gelu + fc2 + residual -> output (c-major)
__global__ __launch_bounds__(256) void k_mlp(const float* __restrict__ xv_in,
    const float* __restrict__ g, const float* __restrict__ b,
    const float* __restrict__ w1, const float* __restrict__ b1,
    const float* __restrict__ w2, const float* __restrict__ b2, float* __restrict__ out){
  __shared__ float xt[64*65];
  __shared__ float ts[64*65];
  int s = blockIdx.x >> 4; int p0 = (blockIdx.x & 15)*64;
  int tid = threadIdx.x; int lane = tid & 63;
  int grp = __builtin_amdgcn_readfirstlane(tid >> 6);
  for (int j=0;j<16;++j){
    int c = grp*16 + j;
    xt[c*65 + lane] = xv_in[((size_t)s*CCH + c)*L2 + p0 + lane];
  }
  __syncthreads();
  float sm=0.f, sq=0.f;
  for (int c=0;c<64;++c){ float v = xt[c*65+lane]; sm+=v; sq+=v*v; }
  float mean = sm*(1.f/64.f);
  float rs = rsqrtf(sq*(1.f/64.f) - mean*mean + 1e-5f);
  int o0 = grp*16;
  float t[16];
  #pragma unroll
  for (int oi=0;oi<16;++oi) t[oi] = b1[o0+oi];
  for (int c=0;c<64;++c){
    float xn = (xt[c*65+lane]-mean)*rs*g[c] + b[c];
    #pragma unroll
    for (int oi=0;oi<16;++oi) t[oi] = fmaf(xn, w1[(o0+oi)*64 + c], t[oi]);
  }
  #pragma unroll
  for (int oi=0;oi<16;++oi) ts[lane*65 + o0+oi] = fgelu(t[oi]);
  __syncthreads();
  int c0 = grp*16;
  float acc[16];
  #pragma unroll
  for (int ci=0;ci<16;++ci) acc[ci] = xt[(c0+ci)*65+lane] + b2[c0+ci];
  for (int o=0;o<64;++o){
    float tv = ts[lane*65 + o];
    #pragma unroll
    for (int ci=0;ci<16;++ci) acc[ci] = fmaf(tv, w2[(c0+ci)*64 + o], acc[ci]);
  }
  #pragma unroll
  for (int ci=0;ci<16;++ci) out[((size_t)s*CCH + c0+ci)*L2 + p0 + lane] = acc[ci];
}

extern "C" void kernel_launch(void* const* d_in, const int* in_sizes, int n_in,
                              void* d_out, int out_size, void* d_ws, size_t ws_size,
                              hipStream_t stream){
  (void)in_sizes; (void)n_in; (void)out_size; (void)ws_size;
  const float* img      = (const float*)d_in[0];
  const float* dz       = (const float*)d_in[1];
  const float* sg       = (const float*)d_in[2];
  const float* norm_g   = (const float*)d_in[3];
  const float* norm_b   = (const float*)d_in[4];
  const float* gn1_g    = (const float*)d_in[5];
  const float* gn1_b    = (const float*)d_in[6];
  const float* conv1_w  = (const float*)d_in[7];
  const float* conv1_b  = (const float*)d_in[8];
  const float* gn2_g    = (const float*)d_in[9];
  const float* gn2_b    = (const float*)d_in[10];
  const float* conv2_w  = (const float*)d_in[11];
  const float* conv2_b  = (const float*)d_in[12];
  const float* skip_w   = (const float*)d_in[13];
  const float* skip_b   = (const float*)d_in[14];
  const float* ln1_g    = (const float*)d_in[15];
  const float* ln1_b    = (const float*)d_in[16];
  const float* ln2_g    = (const float*)d_in[17];
  const float* ln2_b    = (const float*)d_in[18];
  const float* in_proj_w= (const float*)d_in[19];
  const float* dwconv_w = (const float*)d_in[20];
  const float* dwconv_b = (const float*)d_in[21];
  const float* x_proj_w = (const float*)d_in[22];
  const float* dt_proj_w= (const float*)d_in[23];
  const float* dt_proj_b= (const float*)d_in[24];
  const float* A_logs   = (const float*)d_in[25];
  const float* Ds       = (const float*)d_in[26];
  const float* out_norm_g = (const float*)d_in[27];
  const float* out_norm_b = (const float*)d_in[28];
  const float* out_proj_w = (const float*)d_in[29];
  const float* fc1_w    = (const float*)d_in[30];
  const float* fc1_b    = (const float*)d_in[31];
  const float* fc2_w    = (const float*)d_in[32];
  const float* fc2_b    = (const float*)d_in[33];

  float* ws = (float*)d_ws;
  float* x3c    = ws;                       // 1,179,648
  float* xact1  = x3c    + 1179648;         // 1,253,376 (padded)
  float* h1     = xact1  + 1253376;         // 393,216
  float* xact2  = h1     + 393216;          // 417,792 (padded)
  float* xp     = xact2  + 417792;          // 393,216
  float* x_cmaj = xp     + 393216;          // 393,216
  float* z_t    = x_cmaj + 393216;          // 786,432
  float* xc     = z_t    + 786432;          // 786,432
  float* xconv  = xc     + 786432;          // 786,432
  float* t36    = xconv  + 786432;          // 884,736
  float* dtp    = t36    + 884736;          // 3,145,728 (hosts conv1 partials first)
  float* ys_t   = dtp    + 3145728;         // 3,145,728 (hosts conv2 partials first)
  float* yf     = ys_t   + 3145728;         // 786,432
  float* xv     = yf     + 786432;          // 393,216
  float* psum   = xv     + 393216;          // 96
  float* psq    = psum   + 96;              // 96
  float* stats1 = psq    + 96;              // 12
  float* stats2 = stats1 + 12;              // 12
  // aliases into dead regions
  float* part1  = dtp;              // conv1 partials (8 x 393216 = 3,145,728) — consumed before dtp written
  float* part2  = ys_t;             // conv2 partials (3 x 393216) — consumed before ys_t written
  float* hend   = x3c;              // 1,572,864 (x3c+xact1 dead after conv2_split/conv1)
  float* prodA  = xconv;            // 1,572,864 (xconv+t36 dead after xproj/dt_bc); Hin aliases this
  float* u_t    = h1;               // 786,432 (h1+xact2 dead after conv2_split)
  float* Bp     = xp;               // 393,216 (xp dead after ln1_inproj)
  float* Cp     = xc;               // 393,216 (xc dead after dwconv)

  k_ln2d<<<96, 256, 0, stream>>>(img, dz, sg, norm_g, norm_b, x3c);
  k_gnstats_part<<<96, 256, 0, stream>>>(x3c, C3*L2, psum, psq);
  k_gnstats_final<<<6, 64, 0, stream>>>(psum, psq, C3*L2, 1e-5f, stats1);
  k_gnact_pad<<<6*C3, 256, 0, stream>>>(x3c, stats1, gn1_g, gn1_b, C3, xact1);
  k_conv1_split<<<1536, 256, 0, stream>>>(xact1, conv1_w, part1);
  k_reduce1<<<384, 256, 0, stream>>>(part1, conv1_b, h1);
  k_gnstats_part<<<96, 256, 0, stream>>>(h1, CCH*L2, psum, psq);
  k_gnstats_final<<<6, 64, 0, stream>>>(psum, psq, CCH*L2, 1e-5f, stats2);
  k_gnact_pad<<<6*CCH, 256, 0, stream>>>(h1, stats2, gn2_g, gn2_b, CCH, xact2);
  k_conv2_split<<<576, 256, 0, stream>>>(xact2, x3c, conv2_w, skip_w, part2);
  k_reduce2<<<384, 256, 0, stream>>>(part2, conv2_b, skip_b, xp, x_cmaj);
  k_ln1_inproj<<<384, 256, 0, stream>>>(xp, ln1_g, ln1_b, in_proj_w, xc, z_t);
  k_dwconv<<<768, 256, 0, stream>>>(xc, dwconv_w, dwconv_b, xconv);
  k_transp_u<<<192, 256, 0, stream>>>(xconv, u_t);
  k_xproj<<<576, 256, 0, stream>>>(xconv, x_proj_w, t36);
  k_dt_bc<<<384, 256, 0, stream>>>(t36, dt_proj_w, dt_proj_b, dtp, Bp, Cp);
  k_scan_part3<<<384, 256, 0, stream>>>(dtp, u_t, Bp, A_logs, hend, prodA);
  k_scan_fix3<<<192, 256, 0, stream>>>(hend, prodA);
  k_scan_y3<<<384, 256, 0, stream>>>(dtp, u_t, Bp, Cp, A_logs, Ds, prodA, ys_t);
  k_combine2<<<96, 256, 0, stream>>>(ys_t, z_t, out_norm_g, out_norm_b, yf);
  k_outproj<<<384, 256, 0, stream>>>(yf, x_cmaj, out_proj_w, xv);
  k_mlp<<<96, 256, 0, stream>>>(xv, ln2_g, ln2_b, fc1_w, fc1_b, fc2_w, fc2_b, (float*)d_out);
}

// Round 7
// 326.707 us; speedup vs baseline: 1.2338x; 1.0541x over previous
//
#include <hip/hip_runtime.h>
#include <math.h>

// Problem dims
#define BL    6
#define CCH   64
#define C3    192
#define L2    1024
#define DIC   128
#define NST   16
#define K4    4
#define PSTR  1088   // padded plane stride: 34 rows * 32 cols
#define NCH   32     // scan chunks per sequence (32 steps each)

#define LOG2E 1.44269504088896340736f
#define LN2C  0.69314718055994530942f

__device__ __forceinline__ float fexp(float x){ return __builtin_amdgcn_exp2f(x*LOG2E); }
__device__ __forceinline__ float fsilu(float x){ return x / (1.f + fexp(-x)); }
__device__ __forceinline__ float fsoftplus(float x){
  if (x > 20.f) return x;
  return __builtin_amdgcn_logf(1.f + fexp(x)) * LN2C;
}
__device__ __forceinline__ float fgelu(float x){
  return 0.5f*x*(1.f + erff(x*0.70710678118654752440f));
}

// ---------------- A: per-pixel LN of frames + concat [dz, frames_n, sigma] + GN1 stats (atomic)
__global__ __launch_bounds__(256) void k_ln2d(const float* __restrict__ img,
    const float* __restrict__ dz, const float* __restrict__ sg,
    const float* __restrict__ g, const float* __restrict__ b, float* __restrict__ x3c,
    float* __restrict__ psum1, float* __restrict__ psq1){
  __shared__ float ps[4][64], pq[4][64];
  int s = blockIdx.x >> 4;
  int lane = threadIdx.x & 63;
  int cg = threadIdx.x >> 6;
  int p = ((blockIdx.x & 15) << 6) + lane;
  int bsmp = s/3;
  const float* fr = img + (size_t)s*CCH*L2;
  float vals[16]; float sm=0.f, sq=0.f;
  #pragma unroll
  for (int j=0;j<16;++j){
    int c = cg*16+j;
    float v = fr[c*L2+p];
    vals[j]=v; sm+=v; sq+=v*v;
  }
  ps[cg][lane]=sm; pq[cg][lane]=sq;
  __syncthreads();
  sm = ps[0][lane]+ps[1][lane]+ps[2][lane]+ps[3][lane];
  sq = pq[0][lane]+pq[1][lane]+pq[2][lane]+pq[3][lane];
  float mean = sm*(1.f/CCH); float var = sq*(1.f/CCH) - mean*mean;
  float rs = rsqrtf(var + 1e-6f);
  float* o = x3c + (size_t)s*C3*L2;
  const float* dzp = dz + (size_t)bsmp*CCH*L2;
  const float* sgp = sg + (size_t)bsmp*CCH*L2;
  float gsm=0.f, gsq=0.f;   // GN1 stats accumulation over this block's elements
  #pragma unroll
  for (int j=0;j<16;++j){
    int c = cg*16+j;
    float dzv = dzp[c*L2+p];
    float nv  = (vals[j]-mean)*rs*g[c] + b[c];
    float sgv = sgp[c*L2+p];
    o[c*L2+p] = dzv;
    o[(CCH+c)*L2+p] = nv;
    o[(2*CCH+c)*L2+p] = sgv;
    gsm += dzv+nv+sgv; gsq += dzv*dzv+nv*nv+sgv*sgv;
  }
  for (int m=1;m<64;m<<=1){ gsm+=__shfl_xor(gsm,m,64); gsq+=__shfl_xor(gsq,m,64); }
  __syncthreads();
  if (lane==0){ ps[cg][0]=gsm; pq[cg][0]=gsq; }
  __syncthreads();
  if (threadIdx.x==0){
    atomicAdd(psum1+s, ps[0][0]+ps[1][0]+ps[2][0]+ps[3][0]);
    atomicAdd(psq1 +s, pq[0][0]+pq[1][0]+pq[2][0]+pq[3][0]);
  }
}

// ---------------- apply GN affine + SiLU from raw sums, write PADDED plane
__global__ __launch_bounds__(256) void k_gnact_pad(const float* __restrict__ x,
    const float* __restrict__ psum, const float* __restrict__ psq,
    const float* __restrict__ g, const float* __restrict__ b,
    int ch, float inv_n, float eps, float* __restrict__ out){
  int bx = blockIdx.x;
  int s = bx / ch; int c = bx % ch;
  int tid = threadIdx.x;
  float mean = psum[s]*inv_n;
  float var = psq[s]*inv_n - mean*mean;
  float rs = rsqrtf(var + eps);
  float gc = g[c]*rs; float bc = b[c] - mean*rs*g[c];
  float4 v = *(const float4*)(x + (size_t)bx*1024 + tid*4);
  float4 o; o.x = fsilu(v.x*gc+bc); o.y = fsilu(v.y*gc+bc);
  o.z = fsilu(v.z*gc+bc); o.w = fsilu(v.w*gc+bc);
  float* pl = out + (size_t)bx*PSTR;
  *(float4*)(pl + 32 + tid*4) = o;
  float4 z4 = make_float4(0.f,0.f,0.f,0.f);
  if (tid < 8)  *(float4*)(pl + tid*4) = z4;
  else if (tid < 16) *(float4*)(pl + 1056 + (tid-8)*4) = z4;
}

// conv row helper
__device__ __forceinline__ void conv_row_acc(float4& a0, float4& a1, float4 mid, float lf, float rt,
    const float* wp0, const float* wp1){
  float w0=wp0[0], w1=wp0[1], w2=wp0[2];
  a0.x = fmaf(w0,lf,   fmaf(w1,mid.x, fmaf(w2,mid.y, a0.x)));
  a0.y = fmaf(w0,mid.x,fmaf(w1,mid.y, fmaf(w2,mid.z, a0.y)));
  a0.z = fmaf(w0,mid.y,fmaf(w1,mid.z, fmaf(w2,mid.w, a0.z)));
  a0.w = fmaf(w0,mid.z,fmaf(w1,mid.w, fmaf(w2,rt,    a0.w)));
  float v0=wp1[0], v1=wp1[1], v2=wp1[2];
  a1.x = fmaf(v0,lf,   fmaf(v1,mid.x, fmaf(v2,mid.y, a1.x)));
  a1.y = fmaf(v0,mid.x,fmaf(v1,mid.y, fmaf(v2,mid.z, a1.y)));
  a1.z = fmaf(v0,mid.y,fmaf(v1,mid.z, fmaf(v2,mid.w, a1.z)));
  a1.w = fmaf(v0,mid.z,fmaf(v1,mid.w, fmaf(v2,rt,    a1.w)));
}

__device__ __forceinline__ void conv_ci_body(float4 m0, float4 m1, float4 m2, int q,
    const float* wp0, const float* wp1, float4& a0, float4& a1){
  float lf0=__shfl_up(m0.w,1,64), rt0=__shfl_down(m0.x,1,64);
  float lf1=__shfl_up(m1.w,1,64), rt1=__shfl_down(m1.x,1,64);
  float lf2=__shfl_up(m2.w,1,64), rt2=__shfl_down(m2.x,1,64);
  if (q==0){ lf0=0.f; lf1=0.f; lf2=0.f; }
  if (q==7){ rt0=0.f; rt1=0.f; rt2=0.f; }
  conv_row_acc(a0,a1,m0,lf0,rt0, wp0+0, wp1+0);
  conv_row_acc(a0,a1,m1,lf1,rt1, wp0+3, wp1+3);
  conv_row_acc(a0,a1,m2,lf2,rt2, wp0+6, wp1+6);
}

// ---------------- conv1: 192ci -> 64co, split-K=8 (24 ci each), padded input
__global__ __launch_bounds__(256) void k_conv1_split(const float* __restrict__ xact,
    const float* __restrict__ w, float* __restrict__ part){
  int bx = blockIdx.x; int kk = bx&7; int cop=(bx>>3)&31; int s=bx>>8;
  int co0 = cop*2, co1 = co0+1;
  int tid = threadIdx.x; int row = tid>>3; int q = tid&7; int col0 = q*4;
  float4 a0 = make_float4(0.f,0.f,0.f,0.f);
  float4 a1 = make_float4(0.f,0.f,0.f,0.f);
  int ci0 = kk*24;
  const float* pl = xact + ((size_t)s*C3 + ci0)*PSTR + row*32 + col0;
  const float* wp0 = w + (size_t)(co0*C3 + ci0)*9;
  const float* wp1 = w + (size_t)(co1*C3 + ci0)*9;
  float4 m0 = *(const float4*)(pl);
  float4 m1 = *(const float4*)(pl+32);
  float4 m2 = *(const float4*)(pl+64);
  #pragma unroll 2
  for (int i=0;i<24;++i){
    const float* pn = pl + (i<23 ? PSTR : 0);
    float4 n0 = *(const float4*)(pn);
    float4 n1 = *(const float4*)(pn+32);
    float4 n2 = *(const float4*)(pn+64);
    conv_ci_body(m0,m1,m2,q, wp0, wp1, a0, a1);
    wp0 += 9; wp1 += 9; pl = pn; m0=n0; m1=n1; m2=n2;
  }
  float* pp = part + (size_t)kk*(BL*CCH*L2) + ((size_t)s*CCH+co0)*L2 + row*32+col0;
  *(float4*)pp = a0;
  *(float4*)(pp+L2) = a1;
}

// reduce 8 partials + bias -> h1, plus GN2 stats (atomic)
__global__ __launch_bounds__(256) void k_reduce1(const float* __restrict__ part,
    const float* __restrict__ bias, float* __restrict__ h1,
    float* __restrict__ psum2, float* __restrict__ psq2){
  int co = blockIdx.x & 63; int s = blockIdx.x >> 6;
  size_t ofs = ((size_t)s*CCH+co)*L2 + threadIdx.x*4;
  const size_t stride = (size_t)BL*CCH*L2;
  float4 acc = *(const float4*)(part + ofs);
  #pragma unroll
  for (int kk=1;kk<8;++kk){
    float4 r = *(const float4*)(part + (size_t)kk*stride + ofs);
    acc.x += r.x; acc.y += r.y; acc.z += r.z; acc.w += r.w;
  }
  float bv = bias[co];
  acc.x += bv; acc.y += bv; acc.z += bv; acc.w += bv;
  *(float4*)(h1 + ofs) = acc;
  float sm = acc.x+acc.y+acc.z+acc.w;
  float sq = acc.x*acc.x+acc.y*acc.y+acc.z*acc.z+acc.w*acc.w;
  for (int m=1;m<64;m<<=1){ sm+=__shfl_xor(sm,m,64); sq+=__shfl_xor(sq,m,64); }
  __shared__ float s_sm[4], s_sq[4];
  int wv = threadIdx.x>>6;
  if ((threadIdx.x&63)==0){ s_sm[wv]=sm; s_sq[wv]=sq; }
  __syncthreads();
  if (threadIdx.x==0){
    atomicAdd(psum2+s, s_sm[0]+s_sm[1]+s_sm[2]+s_sm[3]);
    atomicAdd(psq2 +s, s_sq[0]+s_sq[1]+s_sq[2]+s_sq[3]);
  }
}

// ---------------- conv2 3x3 (64ci, roles 0/1 = 32ci each) + skip 1x1 (role 2)
__global__ __launch_bounds__(256) void k_conv2_split(const float* __restrict__ xact2,
    const float* __restrict__ x3c, const float* __restrict__ w2,
    const float* __restrict__ wsk, float* __restrict__ part){
  int t = blockIdx.x; int role = t % 3; t /= 3;
  int cop = t & 31; int s = t >> 5;
  int co0 = cop*2, co1 = co0+1;
  int tid = threadIdx.x; int row = tid>>3; int q = tid&7; int col0 = q*4;
  int p = row*32+col0;
  float4 a0 = make_float4(0.f,0.f,0.f,0.f);
  float4 a1 = make_float4(0.f,0.f,0.f,0.f);
  if (role < 2){
    int ci0 = role*32;
    const float* pl = xact2 + ((size_t)s*CCH + ci0)*PSTR + row*32 + col0;
    const float* wp0 = w2 + (size_t)(co0*CCH + ci0)*9;
    const float* wp1 = w2 + (size_t)(co1*CCH + ci0)*9;
    float4 m0 = *(const float4*)(pl);
    float4 m1 = *(const float4*)(pl+32);
    float4 m2 = *(const float4*)(pl+64);
    #pragma unroll 2
    for (int i=0;i<32;++i){
      const float* pn = pl + (i<31 ? PSTR : 0);
      float4 n0 = *(const float4*)(pn);
      float4 n1 = *(const float4*)(pn+32);
      float4 n2 = *(const float4*)(pn+64);
      conv_ci_body(m0,m1,m2,q, wp0, wp1, a0, a1);
      wp0 += 9; wp1 += 9; pl = pn; m0=n0; m1=n1; m2=n2;
    }
  } else {
    const float* x3 = x3c + (size_t)s*C3*L2 + p;
    #pragma unroll 4
    for (int ci=0; ci<C3; ++ci){
      float4 v = *(const float4*)(x3 + (size_t)ci*L2);
      float ws0 = wsk[co0*C3+ci], ws1 = wsk[co1*C3+ci];
      a0.x = fmaf(ws0,v.x,a0.x); a0.y = fmaf(ws0,v.y,a0.y); a0.z = fmaf(ws0,v.z,a0.z); a0.w = fmaf(ws0,v.w,a0.w);
      a1.x = fmaf(ws1,v.x,a1.x); a1.y = fmaf(ws1,v.y,a1.y); a1.z = fmaf(ws1,v.z,a1.z); a1.w = fmaf(ws1,v.w,a1.w);
    }
  }
  float* pp = part + (size_t)role*(BL*CCH*L2) + ((size_t)s*CCH+co0)*L2 + p;
  *(float4*)pp = a0;
  *(float4*)(pp+L2) = a1;
}

__global__ __launch_bounds__(256) void k_reduce2(const float* __restrict__ part,
    const float* __restrict__ b2, const float* __restrict__ bsk,
    float* __restrict__ xp, float* __restrict__ x_cmaj){
  int co = blockIdx.x & 63; int s = blockIdx.x >> 6;
  int p = threadIdx.x*4;
  size_t ofs = ((size_t)s*CCH+co)*L2 + p;
  const size_t stride = (size_t)BL*CCH*L2;
  float4 r0 = *(const float4*)(part + ofs);
  float4 r1 = *(const float4*)(part + stride + ofs);
  float4 r2 = *(const float4*)(part + 2*stride + ofs);
  float bv = b2[co]+bsk[co];
  float4 o;
  o.x = r0.x+r1.x+r2.x+bv;
  o.y = r0.y+r1.y+r2.y+bv;
  o.z = r0.z+r1.z+r2.z+bv;
  o.w = r0.w+r1.w+r2.w+bv;
  *(float4*)(x_cmaj + ofs) = o;
  float* xpb = xp + ((size_t)s*L2 + p)*CCH + co;
  xpb[0] = o.x; xpb[CCH] = o.y; xpb[2*CCH] = o.z; xpb[3*CCH] = o.w;
}

// ---------------- H: ln1 + in_proj, split-o
__global__ __launch_bounds__(256) void k_ln1_inproj(const float* __restrict__ xp,
    const float* __restrict__ g, const float* __restrict__ b, const float* __restrict__ W,
    float* __restrict__ xc, float* __restrict__ z_t){
  __shared__ float xn_s[64*65];
  int bx = blockIdx.x; int oq = bx & 3; int pg = (bx>>2)&15; int s = bx>>6;
  int p0 = pg*64;
  int tid = threadIdx.x; int wv = __builtin_amdgcn_readfirstlane(tid>>6); int lane = tid&63;
  for (int j=0;j<16;++j){
    int pl = wv*16 + j; int p = p0 + pl;
    float v = xp[((size_t)s*L2 + p)*CCH + lane];
    float sm = v, sq = v*v;
    for (int m=1;m<64;m<<=1){ sm += __shfl_xor(sm,m,64); sq += __shfl_xor(sq,m,64); }
    float mean = sm*(1.f/64.f); float var = sq*(1.f/64.f) - mean*mean;
    float rs = rsqrtf(var + 1e-5f);
    xn_s[pl*65 + lane] = (v-mean)*rs*g[lane] + b[lane];
  }
  __syncthreads();
  int px_l = tid & 63;
  int og = __builtin_amdgcn_readfirstlane(tid >> 6);
  int o0 = oq*64 + og*16;
  float acc[16];
  #pragma unroll
  for (int oi=0;oi<16;++oi) acc[oi]=0.f;
  for (int c=0;c<64;++c){
    float xv = xn_s[px_l*65 + c];
    #pragma unroll
    for (int oi=0;oi<16;++oi) acc[oi] = fmaf(W[(o0+oi)*64 + c], xv, acc[oi]);
  }
  int p = p0 + px_l;
  if (oq < 2){
    #pragma unroll
    for (int oi=0;oi<16;++oi) xc[((size_t)s*DIC + o0 + oi)*L2 + p] = acc[oi];
  } else {
    #pragma unroll
    for (int oi=0;oi<16;++oi) z_t[((size_t)s*DIC + (o0-128) + oi)*L2 + p] = acc[oi];
  }
}

// ---------------- I: depthwise 3x3 conv + bias + SiLU
__global__ __launch_bounds__(256) void k_dwconv(const float* __restrict__ xc,
    const float* __restrict__ w, const float* __restrict__ bias, float* __restrict__ xconv){
  int bx = blockIdx.x; int dch = bx & 127; int s = bx >> 7;
  int tid = threadIdx.x; int row = tid>>3; int q = tid&7; int col0 = q*4;
  const float* xr = xc + ((size_t)s*DIC+dch)*L2;
  const float* wp = w + dch*9;
  float bv = bias[dch];
  float4 acc = make_float4(bv,bv,bv,bv);
  #pragma unroll
  for (int dy=-1;dy<=1;++dy){
    int r = row+dy;
    float4 mid = make_float4(0.f,0.f,0.f,0.f);
    if (0<=r && r<32) mid = *(const float4*)(xr + r*32 + col0);
    float lf = __shfl_up(mid.w,1,64); if(q==0) lf=0.f;
    float rt = __shfl_down(mid.x,1,64); if(q==7) rt=0.f;
    float w0=wp[(dy+1)*3], w1=wp[(dy+1)*3+1], w2=wp[(dy+1)*3+2];
    acc.x = fmaf(w0,lf,   fmaf(w1,mid.x, fmaf(w2,mid.y, acc.x)));
    acc.y = fmaf(w0,mid.x,fmaf(w1,mid.y, fmaf(w2,mid.z, acc.y)));
    acc.z = fmaf(w0,mid.y,fmaf(w1,mid.z, fmaf(w2,mid.w, acc.z)));
    acc.w = fmaf(w0,mid.z,fmaf(w1,mid.w, fmaf(w2,rt,    acc.w)));
  }
  acc.x = fsilu(acc.x); acc.y = fsilu(acc.y); acc.z = fsilu(acc.z); acc.w = fsilu(acc.w);
  *(float4*)(xconv + ((size_t)s*DIC+dch)*L2 + row*32+col0) = acc;
}

// ---------------- transpose xconv [s][d][p] -> u_t [s][p][d]
__global__ __launch_bounds__(256) void k_transp_u(const float* __restrict__ xconv,
    float* __restrict__ u_t){
  __shared__ float tb[64*65];
  int bx = blockIdx.x; int dh = bx & 1; int pg = (bx>>1)&15; int s = bx>>5;
  int tid = threadIdx.x;
  for (int i = tid; i < 64*16; i += 256){
    int dr = i>>4; int j4 = (i&15)*4;
    float4 v = *(const float4*)(xconv + ((size_t)(s*DIC + dh*64 + dr))*L2 + pg*64 + j4);
    tb[dr*65 + j4+0] = v.x; tb[dr*65 + j4+1] = v.y;
    tb[dr*65 + j4+2] = v.z; tb[dr*65 + j4+3] = v.w;
  }
  __syncthreads();
  for (int i = tid; i < 64*64; i += 256){
    int px = i>>6; int dd = i&63;
    u_t[((size_t)(s*L2) + pg*64 + px)*DIC + dh*64 + dd] = tb[dd*65 + px];
  }
}

// ---------------- fused x_proj + dt_proj/softplus + B/C extraction
// block = (s,k, pg of 64 px); grid 384
__global__ __launch_bounds__(256) void k_xproj_dt(const float* __restrict__ xconv,
    const float* __restrict__ W, const float* __restrict__ dtw, const float* __restrict__ dtb,
    float* __restrict__ dtp, float* __restrict__ Bp, float* __restrict__ Cp){
  __shared__ float smem[128*68];   // stage1: x tile [d][px]; later reused as t [c][px]
  int bx = blockIdx.x; int pg = bx & 15; int sk = bx >> 4;
  int k = sk & 3; int s = sk >> 2;
  int tid = threadIdx.x;
  // stage 1: load xconv tile (128 d x 64 px)
  for (int i = tid; i < 128*16; i += 256){
    int dr = i>>4; int j4 = (i&15)*4;
    float4 v = *(const float4*)(xconv + ((size_t)(s*DIC + dr))*L2 + pg*64 + j4);
    *(float4*)&smem[dr*68 + j4] = v;
  }
  __syncthreads();
  // stage 2: t[c][px] = sum_d W[k][c][d] * x[d][px], c in 0..35 (9 per cgroup)
  int px = tid & 63;
  int cgrp = __builtin_amdgcn_readfirstlane(tid >> 6);
  int c0 = cgrp*9;
  const float* wb = W + (size_t)(k*36 + c0)*DIC;
  float acc[9];
  #pragma unroll
  for (int ci=0;ci<9;++ci) acc[ci]=0.f;
  for (int d=0; d<DIC; ++d){
    float xv = smem[d*68 + px];
    #pragma unroll
    for (int ci=0;ci<9;++ci) acc[ci] = fmaf(wb[ci*DIC+d], xv, acc[ci]);
  }
  __syncthreads();
  #pragma unroll
  for (int ci=0;ci<9;++ci) smem[(c0+ci)*68 + px] = acc[ci];
  __syncthreads();
  // stage 3: dt = softplus(dt_proj . t[0:4] + bias), write [p][d]
  int d = tid & 127; int half = tid >> 7;
  float w0 = dtw[(k*DIC+d)*4+0], w1 = dtw[(k*DIC+d)*4+1];
  float w2 = dtw[(k*DIC+d)*4+2], w3 = dtw[(k*DIC+d)*4+3];
  float bb = dtb[k*DIC+d];
  float* dout = dtp + ((size_t)sk*L2 + pg*64)*DIC + d;
  for (int pp = half*32; pp < half*32+32; ++pp){
    float r0 = smem[0*68+pp], r1 = smem[1*68+pp], r2 = smem[2*68+pp], r3 = smem[3*68+pp];
    float val = fsoftplus(fmaf(w0,r0,fmaf(w1,r1,fmaf(w2,r2,fmaf(w3,r3,bb)))));
    dout[(size_t)pp*DIC] = val;
  }
  // stage 4: B/C to [p][16]
  float* Bb = Bp + ((size_t)sk*L2 + pg*64)*NST;
  float* Cb = Cp + ((size_t)sk*L2 + pg*64)*NST;
  for (int i = tid; i < 1024; i += 256){
    int pp = i>>4; int n = i&15;
    Bb[pp*NST + n] = smem[(4+n)*68 + pp];
    Cb[pp*NST + n] = smem[(20+n)*68 + pp];
  }
}

// scan pixel for direction k, chunk ch (32 steps), step j
__device__ __forceinline__ int scan_pix32(int ch, int j, int k){
  if (k==0) return ch*32 + j;
  if (k==1) return j*32 + ch;
  if (k==2) return 1023 - (ch*32 + j);
  return 1023 - (j*32 + ch);
}

struct StepB { float dtv, uv; float4 B0,B1,B2,B3; };
__device__ __forceinline__ StepB loadB(const float* db, const float* ub, const float* Bb, int p){
  StepB r;
  r.dtv = db[(size_t)p*DIC]; r.uv = ub[(size_t)p*DIC];
  const float* bp = Bb + p*NST;
  r.B0 = *(const float4*)bp; r.B1 = *(const float4*)(bp+4);
  r.B2 = *(const float4*)(bp+8); r.B3 = *(const float4*)(bp+12);
  return r;
}

// ======== Selective scan: 32 chunks x 32 steps, thread-per-d, manual prefetch ========
__global__ __launch_bounds__(256,2) void k_scan_part3(const float* __restrict__ dtp,
    const float* __restrict__ u_t, const float* __restrict__ Bp,
    const float* __restrict__ A_logs, float* __restrict__ hend, float* __restrict__ prodA){
  int bx = blockIdx.x; int chp = bx & 15; int sk = bx >> 4;
  int k = sk & 3; int s = sk >> 2;
  int tid = threadIdx.x; int d = tid & 127; int ch = chp*2 + (tid>>7);
  float aco[16];
  {
    const float* ab = A_logs + (size_t)(k*DIC+d)*NST;
    #pragma unroll
    for (int n=0;n<16;++n) aco[n] = -LOG2E * fexp(ab[n]);
  }
  float h[16], Pr[16];
  #pragma unroll
  for (int n=0;n<16;++n){ h[n]=0.f; Pr[n]=1.f; }
  const float* db = dtp + (size_t)sk*L2*DIC + d;
  const float* ub = u_t + (size_t)s*L2*DIC + d;
  const float* Bb = Bp + (size_t)sk*L2*NST;
  StepB cur = loadB(db, ub, Bb, scan_pix32(ch, 0, k));
  #pragma unroll 4
  for (int j=0;j<32;++j){
    StepB nxt;
    if (j < 31) nxt = loadB(db, ub, Bb, scan_pix32(ch, j+1, k));
    float tv = cur.dtv*cur.uv;
    #define PSTEP(NI, BV) { float a_ = __builtin_amdgcn_exp2f(cur.dtv*aco[NI]); \
      h[NI] = fmaf(a_, h[NI], tv*(BV)); Pr[NI] *= a_; }
    PSTEP(0,cur.B0.x) PSTEP(1,cur.B0.y) PSTEP(2,cur.B0.z) PSTEP(3,cur.B0.w)
    PSTEP(4,cur.B1.x) PSTEP(5,cur.B1.y) PSTEP(6,cur.B1.z) PSTEP(7,cur.B1.w)
    PSTEP(8,cur.B2.x) PSTEP(9,cur.B2.y) PSTEP(10,cur.B2.z) PSTEP(11,cur.B2.w)
    PSTEP(12,cur.B3.x) PSTEP(13,cur.B3.y) PSTEP(14,cur.B3.z) PSTEP(15,cur.B3.w)
    #undef PSTEP
    cur = nxt;
  }
  size_t base = ((size_t)(sk*NCH + ch)*DIC + d)*NST;
  #pragma unroll
  for (int q4=0;q4<4;++q4){
    *(float4*)(hend + base + q4*4)  = make_float4(h[q4*4],h[q4*4+1],h[q4*4+2],h[q4*4+3]);
    *(float4*)(prodA + base + q4*4) = make_float4(Pr[q4*4],Pr[q4*4+1],Pr[q4*4+2],Pr[q4*4+3]);
  }
}

__global__ __launch_bounds__(256) void k_scan_fix3(const float* __restrict__ hend,
    float* prodA_Hin){
  int t = blockIdx.x*256 + threadIdx.x;
  int n = t & 15; int d = (t>>4) & 127; int sk = t >> 11;
  float H = 0.f;
  for (int ch=0; ch<NCH; ++ch){
    size_t idx = ((size_t)(sk*NCH + ch)*DIC + d)*NST + n;
    float pa = prodA_Hin[idx];
    float he = hend[idx];
    prodA_Hin[idx] = H;
    H = fmaf(pa, H, he);
  }
}

__global__ __launch_bounds__(256,2) void k_scan_y3(const float* __restrict__ dtp,
    const float* __restrict__ u_t, const float* __restrict__ Bp, const float* __restrict__ Cp,
    const float* __restrict__ A_logs, const float* __restrict__ Ds,
    const float* __restrict__ Hin, float* __restrict__ ys_t){
  int bx = blockIdx.x; int chp = bx & 15; int sk = bx >> 4;
  int k = sk & 3; int s = sk >> 2;
  int tid = threadIdx.x; int d = tid & 127; int ch = chp*2 + (tid>>7);
  float aco[16];
  {
    const float* ab = A_logs + (size_t)(k*DIC+d)*NST;
    #pragma unroll
    for (int n=0;n<16;++n) aco[n] = -LOG2E * fexp(ab[n]);
  }
  float Dv = Ds[k*DIC+d];
  float h[16];
  size_t hbase = ((size_t)(sk*NCH + ch)*DIC + d)*NST;
  #pragma unroll
  for (int q4=0;q4<4;++q4){
    float4 hv = *(const float4*)(Hin + hbase + q4*4);
    h[q4*4]=hv.x; h[q4*4+1]=hv.y; h[q4*4+2]=hv.z; h[q4*4+3]=hv.w;
  }
  const float* db = dtp + (size_t)sk*L2*DIC + d;
  const float* ub = u_t + (size_t)s*L2*DIC + d;
  const float* Bb = Bp + (size_t)sk*L2*NST;
  const float* Cb = Cp + (size_t)sk*L2*NST;
  float* yb = ys_t + (size_t)sk*L2*DIC + d;
  int pcur = scan_pix32(ch, 0, k);
  StepB cur = loadB(db, ub, Bb, pcur);
  float4 Cc0 = *(const float4*)(Cb + pcur*NST);
  float4 Cc1 = *(const float4*)(Cb + pcur*NST + 4);
  float4 Cc2 = *(const float4*)(Cb + pcur*NST + 8);
  float4 Cc3 = *(const float4*)(Cb + pcur*NST + 12);
  #pragma unroll 4
  for (int j=0;j<32;++j){
    StepB nxt; float4 Cn0, Cn1, Cn2, Cn3; int pn = pcur;
    if (j < 31){
      pn = scan_pix32(ch, j+1, k);
      nxt = loadB(db, ub, Bb, pn);
      Cn0 = *(const float4*)(Cb + pn*NST);
      Cn1 = *(const float4*)(Cb + pn*NST + 4);
      Cn2 = *(const float4*)(Cb + pn*NST + 8);
      Cn3 = *(const float4*)(Cb + pn*NST + 12);
    }
    float tv = cur.dtv*cur.uv;
    float y0=0.f, y1=0.f, y2=0.f, y3=0.f;
    #define YSTEP(NI, BV, CV, YA) { float a_ = __builtin_amdgcn_exp2f(cur.dtv*aco[NI]); \
      h[NI] = fmaf(a_, h[NI], tv*(BV)); YA = fmaf(h[NI], (CV), YA); }
    YSTEP(0,cur.B0.x,Cc0.x,y0) YSTEP(1,cur.B0.y,Cc0.y,y1) YSTEP(2,cur.B0.z,Cc0.z,y2) YSTEP(3,cur.B0.w,Cc0.w,y3)
    YSTEP(4,cur.B1.x,Cc1.x,y0) YSTEP(5,cur.B1.y,Cc1.y,y1) YSTEP(6,cur.B1.z,Cc1.z,y2) YSTEP(7,cur.B1.w,Cc1.w,y3)
    YSTEP(8,cur.B2.x,Cc2.x,y0) YSTEP(9,cur.B2.y,Cc2.y,y1) YSTEP(10,cur.B2.z,Cc2.z,y2) YSTEP(11,cur.B2.w,Cc2.w,y3)
    YSTEP(12,cur.B3.x,Cc3.x,y0) YSTEP(13,cur.B3.y,Cc3.y,y1) YSTEP(14,cur.B3.z,Cc3.z,y2) YSTEP(15,cur.B3.w,Cc3.w,y3)
    #undef YSTEP
    yb[(size_t)pcur*DIC] = fmaf(cur.uv, Dv, (y0+y1)+(y2+y3));
    cur = nxt; Cc0 = Cn0; Cc1 = Cn1; Cc2 = Cn2; Cc3 = Cn3; pcur = pn;
  }
}

// ---------------- fused: combine 4 dirs + out_norm LN(128) + silu(z) + out_proj + residual
// block = (s, pg of 32 px); grid 192
__global__ __launch_bounds__(256) void k_combine_outproj(const float* __restrict__ ys_t,
    const float* __restrict__ z_t, const float* __restrict__ g, const float* __restrict__ b,
    const float* __restrict__ W, const float* __restrict__ x_cmaj, float* __restrict__ xv){
  __shared__ float yt[128*33];
  int s = blockIdx.x >> 5; int pg = blockIdx.x & 31;
  int tid = threadIdx.x;
  int wv = __builtin_amdgcn_readfirstlane(tid>>6); int lane = tid&63;
  int d0 = lane, d1 = lane+64;
  for (int i=0;i<8;++i){
    int px = i*4 + wv; int p = pg*32 + px;
    const float* yb = ys_t + ((size_t)(s*4)*L2 + p)*DIC;
    float ya = yb[d0] + yb[(size_t)L2*DIC + d0] + yb[(size_t)2*L2*DIC + d0] + yb[(size_t)3*L2*DIC + d0];
    float yc = yb[d1] + yb[(size_t)L2*DIC + d1] + yb[(size_t)2*L2*DIC + d1] + yb[(size_t)3*L2*DIC + d1];
    float sm = ya+yc, sq = ya*ya+yc*yc;
    for (int m=1;m<64;m<<=1){ sm+=__shfl_xor(sm,m,64); sq+=__shfl_xor(sq,m,64); }
    float mean = sm*(1.f/128.f); float var = sq*(1.f/128.f)-mean*mean;
    float rs = rsqrtf(var + 1e-5f);
    float yn0 = (ya-mean)*rs*g[d0] + b[d0];
    float yn1 = (yc-mean)*rs*g[d1] + b[d1];
    float zv0 = z_t[((size_t)s*DIC+d0)*L2 + p];
    float zv1 = z_t[((size_t)s*DIC+d1)*L2 + p];
    yt[d0*33 + px] = yn0 * fsilu(zv0);
    yt[d1*33 + px] = yn1 * fsilu(zv1);
  }
  __syncthreads();
  // out_proj: c = 64 outputs; thread = (cg of 8, px of 32)
  // NOTE: tid>>5 is NOT wave-uniform (wave=64) — must NOT readfirstlane it (R6 bug).
  int px = tid & 31; int cg = tid >> 5;
  int c0 = cg*8;
  float acc[8];
  #pragma unroll
  for (int ci=0;ci<8;++ci) acc[ci]=0.f;
  for (int d=0; d<DIC; ++d){
    float yv = yt[d*33 + px];
    #pragma unroll
    for (int ci=0;ci<8;++ci) acc[ci] = fmaf(W[(c0+ci)*DIC + d], yv, acc[ci]);
  }
  int p = pg*32 + px;
  #pragma unroll
  for (int ci=0;ci<8;++ci){
    size_t base = ((size_t)s*CCH + c0+ci)*L2 + p;
    xv[base] = x_cmaj[base] + acc[ci];
  }
}

// ---------------- M2b: ln2 + fc1 + gelu + fc2 + residual -> output (c-major)
__global__ __launch_bounds__(256) void k_mlp(const float* __restrict__ xv_in,
    const float* __restrict__ g, const float* __restrict__ b,
    const float* __restrict__ w1, const float* __restrict__ b1,
    const float* __restrict__ w2, const float* __restrict__ b2, float* __restrict__ out){
  __shared__ float xt[64*65];
  __shared__ float ts[64*65];
  int s = blockIdx.x >> 4; int p0 = (blockIdx.x & 15)*64;
  int tid = threadIdx.x; int lane = tid & 63;
  int grp = __builtin_amdgcn_readfirstlane(tid >> 6);
  for (int j=0;j<16;++j){
    int c = grp*16 + j;
    xt[c*65 + lane] = xv_in[((size_t)s*CCH + c)*L2 + p0 + lane];
  }
  __syncthreads();
  float sm=0.f, sq=0.f;
  for (int c=0;c<64;++c){ float v = xt[c*65+lane]; sm+=v; sq+=v*v; }
  float mean = sm*(1.f/64.f);
  float rs = rsqrtf(sq*(1.f/64.f) - mean*mean + 1e-5f);
  int o0 = grp*16;
  float t[16];
  #pragma unroll
  for (int oi=0;oi<16;++oi) t[oi] = b1[o0+oi];
  for (int c=0;c<64;++c){
    float xn = (xt[c*65+lane]-mean)*rs*g[c] + b[c];
    #pragma unroll
    for (int oi=0;oi<16;++oi) t[oi] = fmaf(xn, w1[(o0+oi)*64 + c], t[oi]);
  }
  #pragma unroll
  for (int oi=0;oi<16;++oi) ts[lane*65 + o0+oi] = fgelu(t[oi]);
  __syncthreads();
  int c0 = grp*16;
  float acc[16];
  #pragma unroll
  for (int ci=0;ci<16;++ci) acc[ci] = xt[(c0+ci)*65+lane] + b2[c0+ci];
  for (int o=0;o<64;++o){
    float tv = ts[lane*65 + o];
    #pragma unroll
    for (int ci=0;ci<16;++ci) acc[ci] = fmaf(tv, w2[(c0+ci)*64 + o], acc[ci]);
  }
  #pragma unroll
  for (int ci=0;ci<16;++ci) out[((size_t)s*CCH + c0+ci)*L2 + p0 + lane] = acc[ci];
}

extern "C" void kernel_launch(void* const* d_in, const int* in_sizes, int n_in,
                              void* d_out, int out_size, void* d_ws, size_t ws_size,
                              hipStream_t stream){
  (void)in_sizes; (void)n_in; (void)out_size; (void)ws_size;
  const float* img      = (const float*)d_in[0];
  const float* dz       = (const float*)d_in[1];
  const float* sg       = (const float*)d_in[2];
  const float* norm_g   = (const float*)d_in[3];
  const float* norm_b   = (const float*)d_in[4];
  const float* gn1_g    = (const float*)d_in[5];
  const float* gn1_b    = (const float*)d_in[6];
  const float* conv1_w  = (const float*)d_in[7];
  const float* conv1_b  = (const float*)d_in[8];
  const float* gn2_g    = (const float*)d_in[9];
  const float* gn2_b    = (const float*)d_in[10];
  const float* conv2_w  = (const float*)d_in[11];
  const float* conv2_b  = (const float*)d_in[12];
  const float* skip_w   = (const float*)d_in[13];
  const float* skip_b   = (const float*)d_in[14];
  const float* ln1_g    = (const float*)d_in[15];
  const float* ln1_b    = (const float*)d_in[16];
  const float* ln2_g    = (const float*)d_in[17];
  const float* ln2_b    = (const float*)d_in[18];
  const float* in_proj_w= (const float*)d_in[19];
  const float* dwconv_w = (const float*)d_in[20];
  const float* dwconv_b = (const float*)d_in[21];
  const float* x_proj_w = (const float*)d_in[22];
  const float* dt_proj_w= (const float*)d_in[23];
  const float* dt_proj_b= (const float*)d_in[24];
  const float* A_logs   = (const float*)d_in[25];
  const float* Ds       = (const float*)d_in[26];
  const float* out_norm_g = (const float*)d_in[27];
  const float* out_norm_b = (const float*)d_in[28];
  const float* out_proj_w = (const float*)d_in[29];
  const float* fc1_w    = (const float*)d_in[30];
  const float* fc1_b    = (const float*)d_in[31];
  const float* fc2_w    = (const float*)d_in[32];
  const float* fc2_b    = (const float*)d_in[33];

  float* ws = (float*)d_ws;
  float* x3c    = ws;                       // 1,179,648
  float* xact1  = x3c    + 1179648;         // 1,253,376 (padded)
  float* h1     = xact1  + 1253376;         // 393,216
  float* xact2  = h1     + 393216;          // 417,792 (padded)
  float* xp     = xact2  + 417792;          // 393,216
  float* x_cmaj = xp     + 393216;          // 393,216
  float* z_t    = x_cmaj + 393216;          // 786,432
  float* xc     = z_t    + 786432;          // 786,432
  float* xconv  = xc     + 786432;          // 786,432
  float* hole   = xconv  + 786432;          // 884,736 (tail of prodA alias)
  float* dtp    = hole   + 884736;          // 3,145,728 (hosts conv1 partials first)
  float* ys_t   = dtp    + 3145728;         // 3,145,728 (hosts conv2 partials first)
  float* xv     = ys_t   + 3145728;         // 393,216
  float* statsb = xv     + 393216;          // 24 floats: psum1(6) psq1(6) psum2(6) psq2(6)
  float* psum1  = statsb;
  float* psq1   = statsb + 6;
  float* psum2  = statsb + 12;
  float* psq2   = statsb + 18;
  // aliases into dead regions
  float* part1  = dtp;              // conv1 partials (8 x 393216) — consumed before dtp written
  float* part2  = ys_t;             // conv2 partials (3 x 393216) — consumed before ys_t written
  float* hend   = x3c;              // 1,572,864 (x3c+xact1 dead after conv2_split/conv1)
  float* prodA  = xconv;            // 1,572,864 (xconv dead after xproj_dt; extends into hole)
  float* u_t    = h1;               // 786,432 (h1+xact2 dead after conv2_split)
  float* Bp     = xp;               // 393,216 (xp dead after ln1_inproj)
  float* Cp     = xc;               // 393,216 (xc dead after dwconv)

  hipMemsetAsync(statsb, 0, 24*sizeof(float), stream);
  k_ln2d<<<96, 256, 0, stream>>>(img, dz, sg, norm_g, norm_b, x3c, psum1, psq1);
  k_gnact_pad<<<6*C3, 256, 0, stream>>>(x3c, psum1, psq1, gn1_g, gn1_b, C3,
                                        1.f/(C3*L2), 1e-5f, xact1);
  k_conv1_split<<<1536, 256, 0, stream>>>(xact1, conv1_w, part1);
  k_reduce1<<<384, 256, 0, stream>>>(part1, conv1_b, h1, psum2, psq2);
  k_gnact_pad<<<6*CCH, 256, 0, stream>>>(h1, psum2, psq2, gn2_g, gn2_b, CCH,
                                         1.f/(CCH*L2), 1e-5f, xact2);
  k_conv2_split<<<576, 256, 0, stream>>>(xact2, x3c, conv2_w, skip_w, part2);
  k_reduce2<<<384, 256, 0, stream>>>(part2, conv2_b, skip_b, xp, x_cmaj);
  k_ln1_inproj<<<384, 256, 0, stream>>>(xp, ln1_g, ln1_b, in_proj_w, xc, z_t);
  k_dwconv<<<768, 256, 0, stream>>>(xc, dwconv_w, dwconv_b, xconv);
  k_transp_u<<<192, 256, 0, stream>>>(xconv, u_t);
  k_xproj_dt<<<384, 256, 0, stream>>>(xconv, x_proj_w, dt_proj_w, dt_proj_b, dtp, Bp, Cp);
  k_scan_part3<<<384, 256, 0, stream>>>(dtp, u_t, Bp, A_logs, hend, prodA);
  k_scan_fix3<<<192, 256, 0, stream>>>(hend, prodA);
  k_scan_y3<<<384, 256, 0, stream>>>(dtp, u_t, Bp, Cp, A_logs, Ds, prodA, ys_t);
  k_combine_outproj<<<192, 256, 0, stream>>>(ys_t, z_t, out_norm_g, out_norm_b,
                                             out_proj_w, x_cmaj, xv);
  k_mlp<<<96, 256, 0, stream>>>(xv, ln2_g, ln2_b, fc1_w, fc1_b, fc2_w, fc2_b, (float*)d_out);
}

// Round 8
// 316.764 us; speedup vs baseline: 1.2725x; 1.0314x over previous
//
#include <hip/hip_runtime.h>
#include <math.h>

// Problem dims
#define BL    6
#define CCH   64
#define C3    192
#define L2    1024
#define DIC   128
#define NST   16
#define K4    4
#define PSTR  1088   // padded plane stride: 34 rows * 32 cols
#define NCH   32     // scan chunks per sequence (32 steps each)

#define LOG2E 1.44269504088896340736f
#define LN2C  0.69314718055994530942f

__device__ __forceinline__ float fexp(float x){ return __builtin_amdgcn_exp2f(x*LOG2E); }
__device__ __forceinline__ float fsilu(float x){ return x / (1.f + fexp(-x)); }
__device__ __forceinline__ float fsoftplus(float x){
  if (x > 20.f) return x;
  return __builtin_amdgcn_logf(1.f + fexp(x)) * LN2C;
}
__device__ __forceinline__ float fgelu(float x){
  return 0.5f*x*(1.f + erff(x*0.70710678118654752440f));
}

// ---------------- A: per-pixel LN of frames + concat [dz, frames_n, sigma] + GN1 stats (atomic)
__global__ __launch_bounds__(256) void k_ln2d(const float* __restrict__ img,
    const float* __restrict__ dz, const float* __restrict__ sg,
    const float* __restrict__ g, const float* __restrict__ b, float* __restrict__ x3c,
    float* __restrict__ psum1, float* __restrict__ psq1){
  __shared__ float ps[4][64], pq[4][64];
  int s = blockIdx.x >> 4;
  int lane = threadIdx.x & 63;
  int cg = threadIdx.x >> 6;
  int p = ((blockIdx.x & 15) << 6) + lane;
  int bsmp = s/3;
  const float* fr = img + (size_t)s*CCH*L2;
  float vals[16]; float sm=0.f, sq=0.f;
  #pragma unroll
  for (int j=0;j<16;++j){
    int c = cg*16+j;
    float v = fr[c*L2+p];
    vals[j]=v; sm+=v; sq+=v*v;
  }
  ps[cg][lane]=sm; pq[cg][lane]=sq;
  __syncthreads();
  sm = ps[0][lane]+ps[1][lane]+ps[2][lane]+ps[3][lane];
  sq = pq[0][lane]+pq[1][lane]+pq[2][lane]+pq[3][lane];
  float mean = sm*(1.f/CCH); float var = sq*(1.f/CCH) - mean*mean;
  float rs = rsqrtf(var + 1e-6f);
  float* o = x3c + (size_t)s*C3*L2;
  const float* dzp = dz + (size_t)bsmp*CCH*L2;
  const float* sgp = sg + (size_t)bsmp*CCH*L2;
  float gsm=0.f, gsq=0.f;
  #pragma unroll
  for (int j=0;j<16;++j){
    int c = cg*16+j;
    float dzv = dzp[c*L2+p];
    float nv  = (vals[j]-mean)*rs*g[c] + b[c];
    float sgv = sgp[c*L2+p];
    o[c*L2+p] = dzv;
    o[(CCH+c)*L2+p] = nv;
    o[(2*CCH+c)*L2+p] = sgv;
    gsm += dzv+nv+sgv; gsq += dzv*dzv+nv*nv+sgv*sgv;
  }
  for (int m=1;m<64;m<<=1){ gsm+=__shfl_xor(gsm,m,64); gsq+=__shfl_xor(gsq,m,64); }
  __syncthreads();
  if (lane==0){ ps[cg][0]=gsm; pq[cg][0]=gsq; }
  __syncthreads();
  if (threadIdx.x==0){
    atomicAdd(psum1+s, ps[0][0]+ps[1][0]+ps[2][0]+ps[3][0]);
    atomicAdd(psq1 +s, pq[0][0]+pq[1][0]+pq[2][0]+pq[3][0]);
  }
}

// ---------------- apply GN affine + SiLU from raw sums, write PADDED plane
__global__ __launch_bounds__(256) void k_gnact_pad(const float* __restrict__ x,
    const float* __restrict__ psum, const float* __restrict__ psq,
    const float* __restrict__ g, const float* __restrict__ b,
    int ch, float inv_n, float eps, float* __restrict__ out){
  int bx = blockIdx.x;
  int s = bx / ch; int c = bx % ch;
  int tid = threadIdx.x;
  float mean = psum[s]*inv_n;
  float var = psq[s]*inv_n - mean*mean;
  float rs = rsqrtf(var + eps);
  float gc = g[c]*rs; float bc = b[c] - mean*rs*g[c];
  float4 v = *(const float4*)(x + (size_t)bx*1024 + tid*4);
  float4 o; o.x = fsilu(v.x*gc+bc); o.y = fsilu(v.y*gc+bc);
  o.z = fsilu(v.z*gc+bc); o.w = fsilu(v.w*gc+bc);
  float* pl = out + (size_t)bx*PSTR;
  *(float4*)(pl + 32 + tid*4) = o;
  float4 z4 = make_float4(0.f,0.f,0.f,0.f);
  if (tid < 8)  *(float4*)(pl + tid*4) = z4;
  else if (tid < 16) *(float4*)(pl + 1056 + (tid-8)*4) = z4;
}

// conv row helper
__device__ __forceinline__ void conv_row_acc(float4& a0, float4& a1, float4 mid, float lf, float rt,
    const float* wp0, const float* wp1){
  float w0=wp0[0], w1=wp0[1], w2=wp0[2];
  a0.x = fmaf(w0,lf,   fmaf(w1,mid.x, fmaf(w2,mid.y, a0.x)));
  a0.y = fmaf(w0,mid.x,fmaf(w1,mid.y, fmaf(w2,mid.z, a0.y)));
  a0.z = fmaf(w0,mid.y,fmaf(w1,mid.z, fmaf(w2,mid.w, a0.z)));
  a0.w = fmaf(w0,mid.z,fmaf(w1,mid.w, fmaf(w2,rt,    a0.w)));
  float v0=wp1[0], v1=wp1[1], v2=wp1[2];
  a1.x = fmaf(v0,lf,   fmaf(v1,mid.x, fmaf(v2,mid.y, a1.x)));
  a1.y = fmaf(v0,mid.x,fmaf(v1,mid.y, fmaf(v2,mid.z, a1.y)));
  a1.z = fmaf(v0,mid.y,fmaf(v1,mid.z, fmaf(v2,mid.w, a1.z)));
  a1.w = fmaf(v0,mid.z,fmaf(v1,mid.w, fmaf(v2,rt,    a1.w)));
}

__device__ __forceinline__ void conv_ci_body(float4 m0, float4 m1, float4 m2, int q,
    const float* wp0, const float* wp1, float4& a0, float4& a1){
  float lf0=__shfl_up(m0.w,1,64), rt0=__shfl_down(m0.x,1,64);
  float lf1=__shfl_up(m1.w,1,64), rt1=__shfl_down(m1.x,1,64);
  float lf2=__shfl_up(m2.w,1,64), rt2=__shfl_down(m2.x,1,64);
  if (q==0){ lf0=0.f; lf1=0.f; lf2=0.f; }
  if (q==7){ rt0=0.f; rt1=0.f; rt2=0.f; }
  conv_row_acc(a0,a1,m0,lf0,rt0, wp0+0, wp1+0);
  conv_row_acc(a0,a1,m1,lf1,rt1, wp0+3, wp1+3);
  conv_row_acc(a0,a1,m2,lf2,rt2, wp0+6, wp1+6);
}

// ---------------- conv1: 192ci -> 64co, split-K=8 (24 ci each), padded input
__global__ __launch_bounds__(256) void k_conv1_split(const float* __restrict__ xact,
    const float* __restrict__ w, float* __restrict__ part){
  int bx = blockIdx.x; int kk = bx&7; int cop=(bx>>3)&31; int s=bx>>8;
  int co0 = cop*2, co1 = co0+1;
  int tid = threadIdx.x; int row = tid>>3; int q = tid&7; int col0 = q*4;
  float4 a0 = make_float4(0.f,0.f,0.f,0.f);
  float4 a1 = make_float4(0.f,0.f,0.f,0.f);
  int ci0 = kk*24;
  const float* pl = xact + ((size_t)s*C3 + ci0)*PSTR + row*32 + col0;
  const float* wp0 = w + (size_t)(co0*C3 + ci0)*9;
  const float* wp1 = w + (size_t)(co1*C3 + ci0)*9;
  float4 m0 = *(const float4*)(pl);
  float4 m1 = *(const float4*)(pl+32);
  float4 m2 = *(const float4*)(pl+64);
  #pragma unroll 2
  for (int i=0;i<24;++i){
    const float* pn = pl + (i<23 ? PSTR : 0);
    float4 n0 = *(const float4*)(pn);
    float4 n1 = *(const float4*)(pn+32);
    float4 n2 = *(const float4*)(pn+64);
    conv_ci_body(m0,m1,m2,q, wp0, wp1, a0, a1);
    wp0 += 9; wp1 += 9; pl = pn; m0=n0; m1=n1; m2=n2;
  }
  float* pp = part + (size_t)kk*(BL*CCH*L2) + ((size_t)s*CCH+co0)*L2 + row*32+col0;
  *(float4*)pp = a0;
  *(float4*)(pp+L2) = a1;
}

// reduce 8 partials + bias -> h1, plus GN2 stats (atomic)
__global__ __launch_bounds__(256) void k_reduce1(const float* __restrict__ part,
    const float* __restrict__ bias, float* __restrict__ h1,
    float* __restrict__ psum2, float* __restrict__ psq2){
  int co = blockIdx.x & 63; int s = blockIdx.x >> 6;
  size_t ofs = ((size_t)s*CCH+co)*L2 + threadIdx.x*4;
  const size_t stride = (size_t)BL*CCH*L2;
  float4 acc = *(const float4*)(part + ofs);
  #pragma unroll
  for (int kk=1;kk<8;++kk){
    float4 r = *(const float4*)(part + (size_t)kk*stride + ofs);
    acc.x += r.x; acc.y += r.y; acc.z += r.z; acc.w += r.w;
  }
  float bv = bias[co];
  acc.x += bv; acc.y += bv; acc.z += bv; acc.w += bv;
  *(float4*)(h1 + ofs) = acc;
  float sm = acc.x+acc.y+acc.z+acc.w;
  float sq = acc.x*acc.x+acc.y*acc.y+acc.z*acc.z+acc.w*acc.w;
  for (int m=1;m<64;m<<=1){ sm+=__shfl_xor(sm,m,64); sq+=__shfl_xor(sq,m,64); }
  __shared__ float s_sm[4], s_sq[4];
  int wv = threadIdx.x>>6;
  if ((threadIdx.x&63)==0){ s_sm[wv]=sm; s_sq[wv]=sq; }
  __syncthreads();
  if (threadIdx.x==0){
    atomicAdd(psum2+s, s_sm[0]+s_sm[1]+s_sm[2]+s_sm[3]);
    atomicAdd(psq2 +s, s_sq[0]+s_sq[1]+s_sq[2]+s_sq[3]);
  }
}

// ---------------- conv2 3x3 (64ci, roles 0/1 = 32ci each) + skip 1x1 (role 2)
__global__ __launch_bounds__(256) void k_conv2_split(const float* __restrict__ xact2,
    const float* __restrict__ x3c, const float* __restrict__ w2,
    const float* __restrict__ wsk, float* __restrict__ part){
  int t = blockIdx.x; int role = t % 3; t /= 3;
  int cop = t & 31; int s = t >> 5;
  int co0 = cop*2, co1 = co0+1;
  int tid = threadIdx.x; int row = tid>>3; int q = tid&7; int col0 = q*4;
  int p = row*32+col0;
  float4 a0 = make_float4(0.f,0.f,0.f,0.f);
  float4 a1 = make_float4(0.f,0.f,0.f,0.f);
  if (role < 2){
    int ci0 = role*32;
    const float* pl = xact2 + ((size_t)s*CCH + ci0)*PSTR + row*32 + col0;
    const float* wp0 = w2 + (size_t)(co0*CCH + ci0)*9;
    const float* wp1 = w2 + (size_t)(co1*CCH + ci0)*9;
    float4 m0 = *(const float4*)(pl);
    float4 m1 = *(const float4*)(pl+32);
    float4 m2 = *(const float4*)(pl+64);
    #pragma unroll 2
    for (int i=0;i<32;++i){
      const float* pn = pl + (i<31 ? PSTR : 0);
      float4 n0 = *(const float4*)(pn);
      float4 n1 = *(const float4*)(pn+32);
      float4 n2 = *(const float4*)(pn+64);
      conv_ci_body(m0,m1,m2,q, wp0, wp1, a0, a1);
      wp0 += 9; wp1 += 9; pl = pn; m0=n0; m1=n1; m2=n2;
    }
  } else {
    const float* x3 = x3c + (size_t)s*C3*L2 + p;
    #pragma unroll 4
    for (int ci=0; ci<C3; ++ci){
      float4 v = *(const float4*)(x3 + (size_t)ci*L2);
      float ws0 = wsk[co0*C3+ci], ws1 = wsk[co1*C3+ci];
      a0.x = fmaf(ws0,v.x,a0.x); a0.y = fmaf(ws0,v.y,a0.y); a0.z = fmaf(ws0,v.z,a0.z); a0.w = fmaf(ws0,v.w,a0.w);
      a1.x = fmaf(ws1,v.x,a1.x); a1.y = fmaf(ws1,v.y,a1.y); a1.z = fmaf(ws1,v.z,a1.z); a1.w = fmaf(ws1,v.w,a1.w);
    }
  }
  float* pp = part + (size_t)role*(BL*CCH*L2) + ((size_t)s*CCH+co0)*L2 + p;
  *(float4*)pp = a0;
  *(float4*)(pp+L2) = a1;
}

__global__ __launch_bounds__(256) void k_reduce2(const float* __restrict__ part,
    const float* __restrict__ b2, const float* __restrict__ bsk,
    float* __restrict__ xp, float* __restrict__ x_cmaj){
  int co = blockIdx.x & 63; int s = blockIdx.x >> 6;
  int p = threadIdx.x*4;
  size_t ofs = ((size_t)s*CCH+co)*L2 + p;
  const size_t stride = (size_t)BL*CCH*L2;
  float4 r0 = *(const float4*)(part + ofs);
  float4 r1 = *(const float4*)(part + stride + ofs);
  float4 r2 = *(const float4*)(part + 2*stride + ofs);
  float bv = b2[co]+bsk[co];
  float4 o;
  o.x = r0.x+r1.x+r2.x+bv;
  o.y = r0.y+r1.y+r2.y+bv;
  o.z = r0.z+r1.z+r2.z+bv;
  o.w = r0.w+r1.w+r2.w+bv;
  *(float4*)(x_cmaj + ofs) = o;
  float* xpb = xp + ((size_t)s*L2 + p)*CCH + co;
  xpb[0] = o.x; xpb[CCH] = o.y; xpb[2*CCH] = o.z; xpb[3*CCH] = o.w;
}

// ---------------- H: ln1 + in_proj, split-o
__global__ __launch_bounds__(256) void k_ln1_inproj(const float* __restrict__ xp,
    const float* __restrict__ g, const float* __restrict__ b, const float* __restrict__ W,
    float* __restrict__ xc, float* __restrict__ z_t){
  __shared__ float xn_s[64*65];
  int bx = blockIdx.x; int oq = bx & 3; int pg = (bx>>2)&15; int s = bx>>6;
  int p0 = pg*64;
  int tid = threadIdx.x; int wv = __builtin_amdgcn_readfirstlane(tid>>6); int lane = tid&63;
  for (int j=0;j<16;++j){
    int pl = wv*16 + j; int p = p0 + pl;
    float v = xp[((size_t)s*L2 + p)*CCH + lane];
    float sm = v, sq = v*v;
    for (int m=1;m<64;m<<=1){ sm += __shfl_xor(sm,m,64); sq += __shfl_xor(sq,m,64); }
    float mean = sm*(1.f/64.f); float var = sq*(1.f/64.f) - mean*mean;
    float rs = rsqrtf(var + 1e-5f);
    xn_s[pl*65 + lane] = (v-mean)*rs*g[lane] + b[lane];
  }
  __syncthreads();
  int px_l = tid & 63;
  int og = __builtin_amdgcn_readfirstlane(tid >> 6);
  int o0 = oq*64 + og*16;
  float acc[16];
  #pragma unroll
  for (int oi=0;oi<16;++oi) acc[oi]=0.f;
  for (int c=0;c<64;++c){
    float xv = xn_s[px_l*65 + c];
    #pragma unroll
    for (int oi=0;oi<16;++oi) acc[oi] = fmaf(W[(o0+oi)*64 + c], xv, acc[oi]);
  }
  int p = p0 + px_l;
  if (oq < 2){
    #pragma unroll
    for (int oi=0;oi<16;++oi) xc[((size_t)s*DIC + o0 + oi)*L2 + p] = acc[oi];
  } else {
    #pragma unroll
    for (int oi=0;oi<16;++oi) z_t[((size_t)s*DIC + (o0-128) + oi)*L2 + p] = acc[oi];
  }
}

// ---------------- I: depthwise 3x3 conv + bias + SiLU
__global__ __launch_bounds__(256) void k_dwconv(const float* __restrict__ xc,
    const float* __restrict__ w, const float* __restrict__ bias, float* __restrict__ xconv){
  int bx = blockIdx.x; int dch = bx & 127; int s = bx >> 7;
  int tid = threadIdx.x; int row = tid>>3; int q = tid&7; int col0 = q*4;
  const float* xr = xc + ((size_t)s*DIC+dch)*L2;
  const float* wp = w + dch*9;
  float bv = bias[dch];
  float4 acc = make_float4(bv,bv,bv,bv);
  #pragma unroll
  for (int dy=-1;dy<=1;++dy){
    int r = row+dy;
    float4 mid = make_float4(0.f,0.f,0.f,0.f);
    if (0<=r && r<32) mid = *(const float4*)(xr + r*32 + col0);
    float lf = __shfl_up(mid.w,1,64); if(q==0) lf=0.f;
    float rt = __shfl_down(mid.x,1,64); if(q==7) rt=0.f;
    float w0=wp[(dy+1)*3], w1=wp[(dy+1)*3+1], w2=wp[(dy+1)*3+2];
    acc.x = fmaf(w0,lf,   fmaf(w1,mid.x, fmaf(w2,mid.y, acc.x)));
    acc.y = fmaf(w0,mid.x,fmaf(w1,mid.y, fmaf(w2,mid.z, acc.y)));
    acc.z = fmaf(w0,mid.y,fmaf(w1,mid.z, fmaf(w2,mid.w, acc.z)));
    acc.w = fmaf(w0,mid.z,fmaf(w1,mid.w, fmaf(w2,rt,    acc.w)));
  }
  acc.x = fsilu(acc.x); acc.y = fsilu(acc.y); acc.z = fsilu(acc.z); acc.w = fsilu(acc.w);
  *(float4*)(xconv + ((size_t)s*DIC+dch)*L2 + row*32+col0) = acc;
}

// ---------------- fused x_proj + dt_proj/softplus + B/C extraction + u_t transpose (k==0)
// block = (s,k, pg of 64 px); grid 384
__global__ __launch_bounds__(256) void k_xproj_dt(const float* __restrict__ xconv,
    const float* __restrict__ W, const float* __restrict__ dtw, const float* __restrict__ dtb,
    float* __restrict__ dtp, float* __restrict__ Bp, float* __restrict__ Cp,
    float* __restrict__ u_t){
  __shared__ float smem[128*68];   // stage1: x tile [d][px]; later reused as t [c][px]
  int bx = blockIdx.x; int pg = bx & 15; int sk = bx >> 4;
  int k = sk & 3; int s = sk >> 2;
  int tid = threadIdx.x;
  // stage 1: load xconv tile (128 d x 64 px)
  for (int i = tid; i < 128*16; i += 256){
    int dr = i>>4; int j4 = (i&15)*4;
    float4 v = *(const float4*)(xconv + ((size_t)(s*DIC + dr))*L2 + pg*64 + j4);
    *(float4*)&smem[dr*68 + j4] = v;
  }
  __syncthreads();
  // stage 1b (k==0 only): emit u_t [s][p][d] from the tile — replaces k_transp_u
  if (k == 0){
    float* ub = u_t + ((size_t)(s*L2) + pg*64)*DIC;
    for (int i = tid; i < 64*128; i += 256){
      int px2 = i>>7; int dd = i&127;
      ub[(size_t)px2*DIC + dd] = smem[dd*68 + px2];
    }
  }
  // stage 2: t[c][px] = sum_d W[k][c][d] * x[d][px], c in 0..35 (9 per cgroup)
  int px = tid & 63;
  int cgrp = __builtin_amdgcn_readfirstlane(tid >> 6);
  int c0 = cgrp*9;
  const float* wb = W + (size_t)(k*36 + c0)*DIC;
  float acc[9];
  #pragma unroll
  for (int ci=0;ci<9;++ci) acc[ci]=0.f;
  for (int d=0; d<DIC; ++d){
    float xv = smem[d*68 + px];
    #pragma unroll
    for (int ci=0;ci<9;++ci) acc[ci] = fmaf(wb[ci*DIC+d], xv, acc[ci]);
  }
  __syncthreads();
  #pragma unroll
  for (int ci=0;ci<9;++ci) smem[(c0+ci)*68 + px] = acc[ci];
  __syncthreads();
  // stage 3: dt = softplus(dt_proj . t[0:4] + bias), write [p][d]
  int d = tid & 127; int half = tid >> 7;
  float w0 = dtw[(k*DIC+d)*4+0], w1 = dtw[(k*DIC+d)*4+1];
  float w2 = dtw[(k*DIC+d)*4+2], w3 = dtw[(k*DIC+d)*4+3];
  float bb = dtb[k*DIC+d];
  float* dout = dtp + ((size_t)sk*L2 + pg*64)*DIC + d;
  for (int pp = half*32; pp < half*32+32; ++pp){
    float r0 = smem[0*68+pp], r1 = smem[1*68+pp], r2 = smem[2*68+pp], r3 = smem[3*68+pp];
    float val = fsoftplus(fmaf(w0,r0,fmaf(w1,r1,fmaf(w2,r2,fmaf(w3,r3,bb)))));
    dout[(size_t)pp*DIC] = val;
  }
  // stage 4: B/C to [p][16]
  float* Bb = Bp + ((size_t)sk*L2 + pg*64)*NST;
  float* Cb = Cp + ((size_t)sk*L2 + pg*64)*NST;
  for (int i = tid; i < 1024; i += 256){
    int pp = i>>4; int n = i&15;
    Bb[pp*NST + n] = smem[(4+n)*68 + pp];
    Cb[pp*NST + n] = smem[(20+n)*68 + pp];
  }
}

// scan pixel for direction k, chunk ch (32 steps), step j
__device__ __forceinline__ int scan_pix32(int ch, int j, int k){
  if (k==0) return ch*32 + j;
  if (k==1) return j*32 + ch;
  if (k==2) return 1023 - (ch*32 + j);
  return 1023 - (j*32 + ch);
}

struct StepB { float dtv, uv; float4 B0,B1,B2,B3; };
__device__ __forceinline__ StepB loadB(const float* db, const float* ub, const float* Bb, int p){
  StepB r;
  r.dtv = db[(size_t)p*DIC]; r.uv = ub[(size_t)p*DIC];
  const float* bp = Bb + p*NST;
  r.B0 = *(const float4*)bp; r.B1 = *(const float4*)(bp+4);
  r.B2 = *(const float4*)(bp+8); r.B3 = *(const float4*)(bp+12);
  return r;
}

// ======== Selective scan: 32 chunks x 32 steps, thread-per-d, manual prefetch ========
__global__ __launch_bounds__(256,2) void k_scan_part3(const float* __restrict__ dtp,
    const float* __restrict__ u_t, const float* __restrict__ Bp,
    const float* __restrict__ A_logs, float* __restrict__ hend, float* __restrict__ prodA){
  int bx = blockIdx.x; int chp = bx & 15; int sk = bx >> 4;
  int k = sk & 3; int s = sk >> 2;
  int tid = threadIdx.x; int d = tid & 127; int ch = chp*2 + (tid>>7);
  float aco[16];
  {
    const float* ab = A_logs + (size_t)(k*DIC+d)*NST;
    #pragma unroll
    for (int n=0;n<16;++n) aco[n] = -LOG2E * fexp(ab[n]);
  }
  float h[16], Pr[16];
  #pragma unroll
  for (int n=0;n<16;++n){ h[n]=0.f; Pr[n]=1.f; }
  const float* db = dtp + (size_t)sk*L2*DIC + d;
  const float* ub = u_t + (size_t)s*L2*DIC + d;
  const float* Bb = Bp + (size_t)sk*L2*NST;
  StepB cur = loadB(db, ub, Bb, scan_pix32(ch, 0, k));
  #pragma unroll 4
  for (int j=0;j<32;++j){
    StepB nxt;
    if (j < 31) nxt = loadB(db, ub, Bb, scan_pix32(ch, j+1, k));
    float tv = cur.dtv*cur.uv;
    #define PSTEP(NI, BV) { float a_ = __builtin_amdgcn_exp2f(cur.dtv*aco[NI]); \
      h[NI] = fmaf(a_, h[NI], tv*(BV)); Pr[NI] *= a_; }
    PSTEP(0,cur.B0.x) PSTEP(1,cur.B0.y) PSTEP(2,cur.B0.z) PSTEP(3,cur.B0.w)
    PSTEP(4,cur.B1.x) PSTEP(5,cur.B1.y) PSTEP(6,cur.B1.z) PSTEP(7,cur.B1.w)
    PSTEP(8,cur.B2.x) PSTEP(9,cur.B2.y) PSTEP(10,cur.B2.z) PSTEP(11,cur.B2.w)
    PSTEP(12,cur.B3.x) PSTEP(13,cur.B3.y) PSTEP(14,cur.B3.z) PSTEP(15,cur.B3.w)
    #undef PSTEP
    cur = nxt;
  }
  size_t base = ((size_t)(sk*NCH + ch)*DIC + d)*NST;
  #pragma unroll
  for (int q4=0;q4<4;++q4){
    *(float4*)(hend + base + q4*4)  = make_float4(h[q4*4],h[q4*4+1],h[q4*4+2],h[q4*4+3]);
    *(float4*)(prodA + base + q4*4) = make_float4(Pr[q4*4],Pr[q4*4+1],Pr[q4*4+2],Pr[q4*4+3]);
  }
}

__global__ __launch_bounds__(256) void k_scan_fix3(const float* __restrict__ hend,
    float* prodA_Hin){
  int t = blockIdx.x*256 + threadIdx.x;
  int n = t & 15; int d = (t>>4) & 127; int sk = t >> 11;
  float H = 0.f;
  for (int ch=0; ch<NCH; ++ch){
    size_t idx = ((size_t)(sk*NCH + ch)*DIC + d)*NST + n;
    float pa = prodA_Hin[idx];
    float he = hend[idx];
    prodA_Hin[idx] = H;
    H = fmaf(pa, H, he);
  }
}

__global__ __launch_bounds__(256,2) void k_scan_y3(const float* __restrict__ dtp,
    const float* __restrict__ u_t, const float* __restrict__ Bp, const float* __restrict__ Cp,
    const float* __restrict__ A_logs, const float* __restrict__ Ds,
    const float* __restrict__ Hin, float* __restrict__ ys_t){
  int bx = blockIdx.x; int chp = bx & 15; int sk = bx >> 4;
  int k = sk & 3; int s = sk >> 2;
  int tid = threadIdx.x; int d = tid & 127; int ch = chp*2 + (tid>>7);
  float aco[16];
  {
    const float* ab = A_logs + (size_t)(k*DIC+d)*NST;
    #pragma unroll
    for (int n=0;n<16;++n) aco[n] = -LOG2E * fexp(ab[n]);
  }
  float Dv = Ds[k*DIC+d];
  float h[16];
  size_t hbase = ((size_t)(sk*NCH + ch)*DIC + d)*NST;
  #pragma unroll
  for (int q4=0;q4<4;++q4){
    float4 hv = *(const float4*)(Hin + hbase + q4*4);
    h[q4*4]=hv.x; h[q4*4+1]=hv.y; h[q4*4+2]=hv.z; h[q4*4+3]=hv.w;
  }
  const float* db = dtp + (size_t)sk*L2*DIC + d;
  const float* ub = u_t + (size_t)s*L2*DIC + d;
  const float* Bb = Bp + (size_t)sk*L2*NST;
  const float* Cb = Cp + (size_t)sk*L2*NST;
  float* yb = ys_t + (size_t)sk*L2*DIC + d;
  int pcur = scan_pix32(ch, 0, k);
  StepB cur = loadB(db, ub, Bb, pcur);
  float4 Cc0 = *(const float4*)(Cb + pcur*NST);
  float4 Cc1 = *(const float4*)(Cb + pcur*NST + 4);
  float4 Cc2 = *(const float4*)(Cb + pcur*NST + 8);
  float4 Cc3 = *(const float4*)(Cb + pcur*NST + 12);
  #pragma unroll 4
  for (int j=0;j<32;++j){
    StepB nxt; float4 Cn0, Cn1, Cn2, Cn3; int pn = pcur;
    if (j < 31){
      pn = scan_pix32(ch, j+1, k);
      nxt = loadB(db, ub, Bb, pn);
      Cn0 = *(const float4*)(Cb + pn*NST);
      Cn1 = *(const float4*)(Cb + pn*NST + 4);
      Cn2 = *(const float4*)(Cb + pn*NST + 8);
      Cn3 = *(const float4*)(Cb + pn*NST + 12);
    }
    float tv = cur.dtv*cur.uv;
    float y0=0.f, y1=0.f, y2=0.f, y3=0.f;
    #define YSTEP(NI, BV, CV, YA) { float a_ = __builtin_amdgcn_exp2f(cur.dtv*aco[NI]); \
      h[NI] = fmaf(a_, h[NI], tv*(BV)); YA = fmaf(h[NI], (CV), YA); }
    YSTEP(0,cur.B0.x,Cc0.x,y0) YSTEP(1,cur.B0.y,Cc0.y,y1) YSTEP(2,cur.B0.z,Cc0.z,y2) YSTEP(3,cur.B0.w,Cc0.w,y3)
    YSTEP(4,cur.B1.x,Cc1.x,y0) YSTEP(5,cur.B1.y,Cc1.y,y1) YSTEP(6,cur.B1.z,Cc1.z,y2) YSTEP(7,cur.B1.w,Cc1.w,y3)
    YSTEP(8,cur.B2.x,Cc2.x,y0) YSTEP(9,cur.B2.y,Cc2.y,y1) YSTEP(10,cur.B2.z,Cc2.z,y2) YSTEP(11,cur.B2.w,Cc2.w,y3)
    YSTEP(12,cur.B3.x,Cc3.x,y0) YSTEP(13,cur.B3.y,Cc3.y,y1) YSTEP(14,cur.B3.z,Cc3.z,y2) YSTEP(15,cur.B3.w,Cc3.w,y3)
    #undef YSTEP
    yb[(size_t)pcur*DIC] = fmaf(cur.uv, Dv, (y0+y1)+(y2+y3));
    cur = nxt; Cc0 = Cn0; Cc1 = Cn1; Cc2 = Cn2; Cc3 = Cn3; pcur = pn;
  }
}

// ---------------- fused: combine 4 dirs + out_norm LN(128) + silu(z) + out_proj + residual
// block = (s, pg of 16 px); grid 384
__global__ __launch_bounds__(256) void k_combine_outproj(const float* __restrict__ ys_t,
    const float* __restrict__ z_t, const float* __restrict__ g, const float* __restrict__ b,
    const float* __restrict__ W, const float* __restrict__ x_cmaj, float* __restrict__ xv){
  __shared__ float yt[128*17];
  int s = blockIdx.x >> 6; int pg = blockIdx.x & 63;
  int tid = threadIdx.x;
  int wv = __builtin_amdgcn_readfirstlane(tid>>6); int lane = tid&63;
  int d0 = lane, d1 = lane+64;
  for (int i=0;i<4;++i){
    int px = i*4 + wv; int p = pg*16 + px;
    const float* yb = ys_t + ((size_t)(s*4)*L2 + p)*DIC;
    float ya = yb[d0] + yb[(size_t)L2*DIC + d0] + yb[(size_t)2*L2*DIC + d0] + yb[(size_t)3*L2*DIC + d0];
    float yc = yb[d1] + yb[(size_t)L2*DIC + d1] + yb[(size_t)2*L2*DIC + d1] + yb[(size_t)3*L2*DIC + d1];
    float sm = ya+yc, sq = ya*ya+yc*yc;
    for (int m=1;m<64;m<<=1){ sm+=__shfl_xor(sm,m,64); sq+=__shfl_xor(sq,m,64); }
    float mean = sm*(1.f/128.f); float var = sq*(1.f/128.f)-mean*mean;
    float rs = rsqrtf(var + 1e-5f);
    float yn0 = (ya-mean)*rs*g[d0] + b[d0];
    float yn1 = (yc-mean)*rs*g[d1] + b[d1];
    float zv0 = z_t[((size_t)s*DIC+d0)*L2 + p];
    float zv1 = z_t[((size_t)s*DIC+d1)*L2 + p];
    yt[d0*17 + px] = yn0 * fsilu(zv0);
    yt[d1*17 + px] = yn1 * fsilu(zv1);
  }
  __syncthreads();
  // out_proj: thread = (cg of 16 groups x 4 ch, px of 16). per-lane indices (NOT readfirstlane).
  int px = tid & 15; int cg = tid >> 4;
  int c0 = cg*4;
  float a0=0.f,a1=0.f,a2=0.f,a3=0.f;
  for (int d=0; d<DIC; ++d){
    float yv = yt[d*17 + px];
    a0 = fmaf(W[(c0+0)*DIC + d], yv, a0);
    a1 = fmaf(W[(c0+1)*DIC + d], yv, a1);
    a2 = fmaf(W[(c0+2)*DIC + d], yv, a2);
    a3 = fmaf(W[(c0+3)*DIC + d], yv, a3);
  }
  int p = pg*16 + px;
  size_t base = ((size_t)s*CCH + c0)*L2 + p;
  xv[base]      = x_cmaj[base]      + a0;
  xv[base+L2]   = x_cmaj[base+L2]   + a1;
  xv[base+2*L2] = x_cmaj[base+2*L2] + a2;
  xv[base+3*L2] = x_cmaj[base+3*L2] + a3;
}

// ---------------- M2b: ln2 + fc1 + gelu + fc2 + residual -> output (c-major)
// block = (s, pg of 32 px); grid 192
__global__ __launch_bounds__(256) void k_mlp(const float* __restrict__ xv_in,
    const float* __restrict__ g, const float* __restrict__ b,
    const float* __restrict__ w1, const float* __restrict__ b1,
    const float* __restrict__ w2, const float* __restrict__ b2, float* __restrict__ out){
  __shared__ float xt[64*33];
  __shared__ float ts[32*65];
  int s = blockIdx.x >> 5; int p0 = (blockIdx.x & 31)*32;
  int tid = threadIdx.x; int px = tid & 31; int cg = tid >> 5;   // cg 0..7 (per-lane)
  #pragma unroll
  for (int j=0;j<8;++j){
    int c = cg*8 + j;
    xt[c*33 + px] = xv_in[((size_t)s*CCH + c)*L2 + p0 + px];
  }
  __syncthreads();
  float sm=0.f, sq=0.f;
  for (int c=0;c<64;++c){ float v = xt[c*33+px]; sm+=v; sq+=v*v; }
  float mean = sm*(1.f/64.f);
  float rs = rsqrtf(sq*(1.f/64.f) - mean*mean + 1e-5f);
  int o0 = cg*8;
  float t[8];
  #pragma unroll
  for (int oi=0;oi<8;++oi) t[oi] = b1[o0+oi];
  for (int c=0;c<64;++c){
    float xn = (xt[c*33+px]-mean)*rs*g[c] + b[c];
    #pragma unroll
    for (int oi=0;oi<8;++oi) t[oi] = fmaf(xn, w1[(o0+oi)*64 + c], t[oi]);
  }
  #pragma unroll
  for (int oi=0;oi<8;++oi) ts[px*65 + o0+oi] = fgelu(t[oi]);
  __syncthreads();
  int c0 = cg*8;
  float acc[8];
  #pragma unroll
  for (int ci=0;ci<8;++ci) acc[ci] = xt[(c0+ci)*33+px] + b2[c0+ci];
  for (int o=0;o<64;++o){
    float tv = ts[px*65 + o];
    #pragma unroll
    for (int ci=0;ci<8;++ci) acc[ci] = fmaf(tv, w2[(c0+ci)*64 + o], acc[ci]);
  }
  #pragma unroll
  for (int ci=0;ci<8;++ci) out[((size_t)s*CCH + c0+ci)*L2 + p0 + px] = acc[ci];
}

extern "C" void kernel_launch(void* const* d_in, const int* in_sizes, int n_in,
                              void* d_out, int out_size, void* d_ws, size_t ws_size,
                              hipStream_t stream){
  (void)in_sizes; (void)n_in; (void)out_size; (void)ws_size;
  const float* img      = (const float*)d_in[0];
  const float* dz       = (const float*)d_in[1];
  const float* sg       = (const float*)d_in[2];
  const float* norm_g   = (const float*)d_in[3];
  const float* norm_b   = (const float*)d_in[4];
  const float* gn1_g    = (const float*)d_in[5];
  const float* gn1_b    = (const float*)d_in[6];
  const float* conv1_w  = (const float*)d_in[7];
  const float* conv1_b  = (const float*)d_in[8];
  const float* gn2_g    = (const float*)d_in[9];
  const float* gn2_b    = (const float*)d_in[10];
  const float* conv2_w  = (const float*)d_in[11];
  const float* conv2_b  = (const float*)d_in[12];
  const float* skip_w   = (const float*)d_in[13];
  const float* skip_b   = (const float*)d_in[14];
  const float* ln1_g    = (const float*)d_in[15];
  const float* ln1_b    = (const float*)d_in[16];
  const float* ln2_g    = (const float*)d_in[17];
  const float* ln2_b    = (const float*)d_in[18];
  const float* in_proj_w= (const float*)d_in[19];
  const float* dwconv_w = (const float*)d_in[20];
  const float* dwconv_b = (const float*)d_in[21];
  const float* x_proj_w = (const float*)d_in[22];
  const float* dt_proj_w= (const float*)d_in[23];
  const float* dt_proj_b= (const float*)d_in[24];
  const float* A_logs   = (const float*)d_in[25];
  const float* Ds       = (const float*)d_in[26];
  const float* out_norm_g = (const float*)d_in[27];
  const float* out_norm_b = (const float*)d_in[28];
  const float* out_proj_w = (const float*)d_in[29];
  const float* fc1_w    = (const float*)d_in[30];
  const float* fc1_b    = (const float*)d_in[31];
  const float* fc2_w    = (const float*)d_in[32];
  const float* fc2_b    = (const float*)d_in[33];

  float* ws = (float*)d_ws;
  float* x3c    = ws;                       // 1,179,648
  float* xact1  = x3c    + 1179648;         // 1,253,376 (padded)
  float* h1     = xact1  + 1253376;         // 393,216
  float* xact2  = h1     + 393216;          // 417,792 (padded)
  float* xp     = xact2  + 417792;          // 393,216
  float* x_cmaj = xp     + 393216;          // 393,216
  float* z_t    = x_cmaj + 393216;          // 786,432
  float* xc     = z_t    + 786432;          // 786,432
  float* xconv  = xc     + 786432;          // 786,432
  float* hole   = xconv  + 786432;          // 884,736 (tail of prodA alias)
  float* dtp    = hole   + 884736;          // 3,145,728 (hosts conv1 partials first)
  float* ys_t   = dtp    + 3145728;         // 3,145,728 (hosts conv2 partials first)
  float* xv     = ys_t   + 3145728;         // 393,216
  float* statsb = xv     + 393216;          // 24 floats
  float* psum1  = statsb;
  float* psq1   = statsb + 6;
  float* psum2  = statsb + 12;
  float* psq2   = statsb + 18;
  // aliases into dead regions
  float* part1  = dtp;              // conv1 partials (8 x 393216) — consumed before dtp written
  float* part2  = ys_t;             // conv2 partials (3 x 393216) — consumed before ys_t written
  float* hend   = x3c;              // 1,572,864 (x3c+xact1 dead after conv2_split/conv1)
  float* prodA  = xconv;            // 1,572,864 (xconv dead after xproj_dt; extends into hole)
  float* u_t    = h1;               // 786,432 (h1+xact2 dead after conv2_split/gnact2)
  float* Bp     = xp;               // 393,216 (xp dead after ln1_inproj)
  float* Cp     = xc;               // 393,216 (xc dead after dwconv)

  hipMemsetAsync(statsb, 0, 24*sizeof(float), stream);
  k_ln2d<<<96, 256, 0, stream>>>(img, dz, sg, norm_g, norm_b, x3c, psum1, psq1);
  k_gnact_pad<<<6*C3, 256, 0, stream>>>(x3c, psum1, psq1, gn1_g, gn1_b, C3,
                                        1.f/(C3*L2), 1e-5f, xact1);
  k_conv1_split<<<1536, 256, 0, stream>>>(xact1, conv1_w, part1);
  k_reduce1<<<384, 256, 0, stream>>>(part1, conv1_b, h1, psum2, psq2);
  k_gnact_pad<<<6*CCH, 256, 0, stream>>>(h1, psum2, psq2, gn2_g, gn2_b, CCH,
                                         1.f/(CCH*L2), 1e-5f, xact2);
  k_conv2_split<<<576, 256, 0, stream>>>(xact2, x3c, conv2_w, skip_w, part2);
  k_reduce2<<<384, 256, 0, stream>>>(part2, conv2_b, skip_b, xp, x_cmaj);
  k_ln1_inproj<<<384, 256, 0, stream>>>(xp, ln1_g, ln1_b, in_proj_w, xc, z_t);
  k_dwconv<<<768, 256, 0, stream>>>(xc, dwconv_w, dwconv_b, xconv);
  k_xproj_dt<<<384, 256, 0, stream>>>(xconv, x_proj_w, dt_proj_w, dt_proj_b, dtp, Bp, Cp, u_t);
  k_scan_part3<<<384, 256, 0, stream>>>(dtp, u_t, Bp, A_logs, hend, prodA);
  k_scan_fix3<<<192, 256, 0, stream>>>(hend, prodA);
  k_scan_y3<<<384, 256, 0, stream>>>(dtp, u_t, Bp, Cp, A_logs, Ds, prodA, ys_t);
  k_combine_outproj<<<384, 256, 0, stream>>>(ys_t, z_t, out_norm_g, out_norm_b,
                                             out_proj_w, x_cmaj, xv);
  k_mlp<<<192, 256, 0, stream>>>(xv, ln2_g, ln2_b, fc1_w, fc1_b, fc2_w, fc2_b, (float*)d_out);
}